// Round 7
// baseline (557.383 us; speedup 1.0000x reference)
//
#include <hip/hip_runtime.h>
#include <hip/hip_bf16.h>

// Problem constants
#define NT 4301   // total tokens
#define NP 4201   // patch tokens (use *_p weights)
#define NDET 100  // detection tokens (use *_d weights)
#define DMODEL 768
#define NHEAD 12
#define HD 64
#define LN_EPS 1e-5f
#define LOG2E 1.4426950408889634f
#define QSCALE (0.125f * LOG2E)   // attn scale folded with log2(e): softmax in exp2 domain
#define NTP 4352                  // padded token count (17*256 = 68*64)
#define NCHUNK 68                 // ceil(4301/64)
#define NQB 17                    // attn q-blocks (256 rows each)
#define FRAGSZ 512                // elems per frag blob: 64 lanes x 8 bf16
#define CHUNKSZ 4096              // elems per (head,chunk): 8 frags x 512

typedef __hip_bfloat16 bf16;
typedef __attribute__((ext_vector_type(4))) float f32x4;
typedef __attribute__((ext_vector_type(8))) short frag8;  // 8 bf16 in 4 VGPRs
typedef __attribute__((ext_vector_type(2))) unsigned int u32x2;

// permlane swap helpers (gfx950). Builtin returns {new_dst, new_src}; both used.
static __device__ __forceinline__ void permlane32_swap(unsigned& a, unsigned& b) {
#if __has_builtin(__builtin_amdgcn_permlane32_swap)
    u32x2 r = __builtin_amdgcn_permlane32_swap(a, b, false, false);
    a = r[0]; b = r[1];
#else
    asm("v_permlane32_swap_b32 %0, %1" : "+v"(a), "+v"(b));
#endif
}
static __device__ __forceinline__ void permlane16_swap(unsigned& a, unsigned& b) {
#if __has_builtin(__builtin_amdgcn_permlane16_swap)
    u32x2 r = __builtin_amdgcn_permlane16_swap(a, b, false, false);
    a = r[0]; b = r[1];
#else
    asm("v_permlane16_swap_b32 %0, %1" : "+v"(a), "+v"(b));
#endif
}

// native exp2 (no OCML guard code); v_exp_f32 handles the full f32 range.
static __device__ __forceinline__ float fast_exp2(float x) {
#if __has_builtin(__builtin_amdgcn_exp2f)
    return __builtin_amdgcn_exp2f(x);
#else
    return __builtin_exp2f(x);
#endif
}

// Pack two f32 -> bf16x2 (a -> low16, b -> high16) in 3 VALU ops, no asm.
// Round-half-up (add 0x8000 before truncate) ~= RNE for softmax P values;
// replaces the ~12-VALU software-RNE __float22bfloat162_rn.
static __device__ __forceinline__ unsigned pack_bf16_rh(float a, float b) {
    unsigned ua = __builtin_bit_cast(unsigned, a) + 0x8000u;
    unsigned ub = __builtin_bit_cast(unsigned, b) + 0x8000u;
    return __builtin_amdgcn_perm(ub, ua, 0x07060302u);
}

// async global->LDS, 16B per lane. LDS dest = wave-uniform base + lane*16
// (m104); global src is per-lane. Frag blobs are exactly 64 lanes x 16B.
static __device__ __forceinline__ void gload16(const bf16* g, bf16* l) {
    __builtin_amdgcn_global_load_lds(
        (const __attribute__((address_space(1))) void*)g,
        (__attribute__((address_space(3))) void*)l, 16, 0, 0);
}

// ---------------------------------------------------------------------------
// One fused cast: x + 8 weight matrices fp32->bf16 into contiguous ws region
// ---------------------------------------------------------------------------
__global__ __launch_bounds__(256) void cast_all_kernel(
    const float* __restrict__ x,
    const float* __restrict__ w0, const float* __restrict__ w1,
    const float* __restrict__ w2, const float* __restrict__ w3,
    const float* __restrict__ w4, const float* __restrict__ w5,
    const float* __restrict__ w6, const float* __restrict__ w7,
    bf16* __restrict__ dst, int nx, int nw, int total) {
    int i4 = (blockIdx.x * 256 + threadIdx.x) * 4;
    if (i4 >= total) return;
    const float* s;
    int off;
    if (i4 < nx) {
        s = x; off = i4;
    } else {
        int r = i4 - nx;
        int w = r / nw;
        off = r - w * nw;
        s = w0;
        if (w == 1) s = w1; else if (w == 2) s = w2; else if (w == 3) s = w3;
        else if (w == 4) s = w4; else if (w == 5) s = w5;
        else if (w == 6) s = w6; else if (w == 7) s = w7;
    }
    float4 v = *(const float4*)(s + off);
    bf16 o[4] = {__float2bfloat16(v.x), __float2bfloat16(v.y),
                 __float2bfloat16(v.z), __float2bfloat16(v.w)};
    *(ushort4*)(dst + i4) = *(ushort4*)o;
}

// ---------------------------------------------------------------------------
// Fused QKV v2: one block per (row-tile, head) computes Q, K, V together.
// grid = (68, 12). Outputs: Q*QSCALE row-major; K/V pre-swizzled frag order.
// ---------------------------------------------------------------------------
__global__ __launch_bounds__(256, 4) void qkv_kernel(
    const bf16* __restrict__ xb, const bf16* __restrict__ wbase,
    const float* __restrict__ bq_p, const float* __restrict__ bq_d,
    const float* __restrict__ bv_p, const float* __restrict__ bv_d,
    bf16* __restrict__ Qb, bf16* __restrict__ Ksw, bf16* __restrict__ Vsw) {
    __shared__ bf16 As[64][32];
    __shared__ bf16 Bs[192][32];   // rows 0-63: wq, 64-127: wk, 128-191: wv

    const int tid = threadIdx.x;
    const int wave = tid >> 6, lane = tid & 63;
    const int quad = lane >> 4, l16 = lane & 15;
    const int bx = blockIdx.x;
    const int h = blockIdx.y;
    const int is_det = bx >= 66;
    const int row0 = is_det ? NP + (bx - 66) * 64 : bx * 64;
    const int Mlim = is_det ? NT : NP;
    const int col0 = h * 64;
    const size_t nw = (size_t)DMODEL * DMODEL;
    const bf16* W = wbase + (is_det ? 3 * nw : 0);

    const f32x4 z4 = {0.f, 0.f, 0.f, 0.f};
    f32x4 acc[4][3];
#pragma unroll
    for (int r4 = 0; r4 < 4; ++r4)
#pragma unroll
        for (int f = 0; f < 3; ++f) acc[r4][f] = z4;

    const int srow = tid >> 2;          // 0..63
    const int scol8 = (tid & 3) * 8;    // 0,8,16,24
    int a_r = row0 + srow;
    if (a_r >= Mlim) a_r = Mlim - 1;
    const bf16* ap = xb + (size_t)a_r * DMODEL + scol8;
    const bf16* bp = W + (size_t)(col0 + srow) * DMODEL + scol8;

    uint4 areg  = *(const uint4*)(ap);
    uint4 breg0 = *(const uint4*)(bp);
    uint4 breg1 = *(const uint4*)(bp + nw);
    uint4 breg2 = *(const uint4*)(bp + 2 * nw);

    for (int k0 = 0; k0 < DMODEL; k0 += 32) {
        __syncthreads();
        *(uint4*)(&As[srow][scol8]) = areg;
        *(uint4*)(&Bs[srow][scol8]) = breg0;
        *(uint4*)(&Bs[64 + srow][scol8]) = breg1;
        *(uint4*)(&Bs[128 + srow][scol8]) = breg2;
        if (k0 + 32 < DMODEL) {
            areg  = *(const uint4*)(ap + k0 + 32);
            breg0 = *(const uint4*)(bp + k0 + 32);
            breg1 = *(const uint4*)(bp + nw + k0 + 32);
            breg2 = *(const uint4*)(bp + 2 * nw + k0 + 32);
        }
        __asm__ volatile("s_waitcnt lgkmcnt(0)" ::: "memory");
        __builtin_amdgcn_s_barrier();   // prefetch vmcnt stays in flight
        __asm__ volatile("" ::: "memory");
        frag8 af[4], bfr[3];
#pragma unroll
        for (int r4 = 0; r4 < 4; ++r4)
            af[r4] = *(const frag8*)(&As[r4 * 16 + l16][quad * 8]);
#pragma unroll
        for (int f = 0; f < 3; ++f)
            bfr[f] = *(const frag8*)(&Bs[wave * 48 + f * 16 + l16][quad * 8]);
#pragma unroll
        for (int r4 = 0; r4 < 4; ++r4)
#pragma unroll
            for (int f = 0; f < 3; ++f)
                acc[r4][f] = __builtin_amdgcn_mfma_f32_16x16x32_bf16(af[r4], bfr[f], acc[r4][f], 0, 0, 0);
        __asm__ volatile("" ::: "memory");
    }

    // epilogue: wave w covers logical cols [w*48, w*48+48); 16-col group oc=3w+f
#pragma unroll
    for (int f = 0; f < 3; ++f) {
        const int oc = 3 * wave + f;          // 0..11
        const int opi = oc >> 2;              // 0=Q 1=K 2=V
        const int cin = (oc & 3) * 16 + l16;  // head-dim 0..63
        const int c = col0 + cin;             // global dim
        float bv = 0.f, scale = 1.f;
        if (opi == 0) { bv = (is_det ? bq_d : bq_p)[c]; scale = QSCALE; }
        else if (opi == 2) { bv = (is_det ? bv_d : bv_p)[c]; }
#pragma unroll
        for (int r4 = 0; r4 < 4; ++r4) {
#pragma unroll
            for (int j = 0; j < 4; ++j) {
                const int r = row0 + r4 * 16 + quad * 4 + j;
                if (r >= Mlim) continue;
                const bf16 val = __float2bfloat16((acc[r4][f][j] + bv) * scale);
                if (opi == 0) {
                    Qb[(size_t)r * DMODEL + c] = val;
                } else if (opi == 1) {
                    const int cc = r >> 6, tf = (r >> 4) & 3, ln = r & 15;
                    const int s = cin >> 5, qd = (cin >> 3) & 3, je = cin & 7;
                    Ksw[((size_t)(h * NCHUNK + cc) * 8 + tf * 2 + s) * FRAGSZ +
                        (qd * 16 + ln) * 8 + je] = val;
                } else {
                    const int t = cin >> 4, le = cin & 15;
                    const int cc = r >> 6, rr = r & 63;
                    const int sv = rr >> 5, qv = (rr >> 3) & 3, je = rr & 7;
                    Vsw[((size_t)(h * NCHUNK + cc) * 8 + t * 2 + sv) * FRAGSZ +
                        (qv * 16 + le) * 8 + je] = val;
                }
            }
        }
    }
}

// ---------------------------------------------------------------------------
// Flash attention v14: 8-wave blocks (512 thr, 256 q-rows). Same 32 KB K/V
// double-buffer now feeds 8 wave-computes (vs 4) -> LDS-per-wave halves;
// __launch_bounds__(512, 8) caps regs at 64 (v13 used 52) -> target 4
// blocks/CU = 32 waves/CU (v13 measured ~9). Grid 17*12*nsplit fits one
// residency pass. Staging: 2 gload_lds/wave, counted vmcnt(2).
// ---------------------------------------------------------------------------
__global__ __launch_bounds__(512, 8) void attn_kernel(
    const bf16* __restrict__ Q, const bf16* __restrict__ Ksw,
    const bf16* __restrict__ Vsw, float* __restrict__ O_part,
    float* __restrict__ l_part, int cpb) {
    __shared__ bf16 KV[2][16][FRAGSZ];   // [buf][frag: 0-7 K, 8-15 V][lane*8]

    const int tid = threadIdx.x;
    const int wave = tid >> 6, lane = tid & 63;   // wave 0..7
    const int quad = lane >> 4, l16 = lane & 15;

    // decode (bx, h, z) from 1D id; XCD-chunked when blocks/XCD % NQB == 0
    int bx, h, z;
    {
        const int id = blockIdx.x;
        const int nblk = gridDim.x;
        const int per = nblk >> 3;
        if ((nblk & 7) == 0 && per % NQB == 0) {
            const int ppx = per / NQB;                // (h,z) pairs per XCD
            const int q = id >> 3;
            const int pair = (id & 7) * ppx + q / NQB;
            bx = q % NQB;
            h = pair % NHEAD; z = pair / NHEAD;
        } else {
            bx = id % NQB; h = (id / NQB) % NHEAD; z = id / (NQB * NHEAD);
        }
    }
    const int qbase = bx * 256;
    const int hoff = h * HD;
    const int c0 = z * cpb, c1 = c0 + cpb;

    frag8 ones;
#pragma unroll
    for (int j = 0; j < 8; ++j) ones[j] = (short)0x3F80;

    // Q fragments for 2 row-groups: rows qbase + wave*32 + g*16 + l16.
    frag8 qf[2][2];
#pragma unroll
    for (int g = 0; g < 2; ++g) {
        int qr = qbase + wave * 32 + g * 16 + l16;
        if (qr >= NT) qr = NT - 1;
#pragma unroll
        for (int s = 0; s < 2; ++s)
            qf[g][s] = *(const frag8*)(Q + (size_t)qr * DMODEL + hoff + s * 32 + quad * 8);
    }

    // staging: waves 0-3 -> K frags {2w,2w+1}; waves 4-7 -> V frags {2w',2w'+1}
    const bf16* kb0 = Ksw + (size_t)h * NCHUNK * CHUNKSZ + lane * 8;
    const bf16* vb0 = Vsw + (size_t)h * NCHUNK * CHUNKSZ + lane * 8;
    const bf16* sb = (wave < 4) ? kb0 : vb0;
    const int foff = (wave & 3) * 2;      // frag index within K or V blob
    const int fbase = 2 * wave;           // LDS frag row (0..15)

    const f32x4 z4 = {0.f, 0.f, 0.f, 0.f};
    f32x4 accO[2][4], accL[2];
#pragma unroll
    for (int g = 0; g < 2; ++g) {
        accL[g] = z4;
#pragma unroll
        for (int t = 0; t < 4; ++t) accO[g][t] = z4;
    }

    // drain qf loads so loop vmcnt counts only stage loads
    __asm__ volatile("s_waitcnt vmcnt(0)" ::: "memory");

    // prologue: stage chunk c0 into buffer 0 (2 gload_lds per wave)
    {
        const bf16* s = sb + (size_t)c0 * CHUNKSZ + foff * FRAGSZ;
#pragma unroll
        for (int i = 0; i < 2; ++i)
            gload16(s + i * FRAGSZ, &KV[0][fbase + i][0]);
    }

    int p = 0;
    for (int c = c0; c < c1; ++c) {
        if (c + 1 < c1) {
            // prefetch next chunk into the other buffer; keep it in flight
            const bf16* s = sb + (size_t)(c + 1) * CHUNKSZ + foff * FRAGSZ;
#pragma unroll
            for (int i = 0; i < 2; ++i)
                gload16(s + i * FRAGSZ, &KV[p ^ 1][fbase + i][0]);
            __asm__ volatile("s_waitcnt vmcnt(2)" ::: "memory");
        } else {
            __asm__ volatile("s_waitcnt vmcnt(0)" ::: "memory");
        }
        __builtin_amdgcn_s_barrier();     // all 16 frags of chunk c visible
        __asm__ volatile("" ::: "memory");

        // S^T = K @ Q^T; kf read per-t at point of use (8 live K VGPRs)
        f32x4 S[2][4];
#pragma unroll
        for (int t = 0; t < 4; ++t) {
            const frag8 k0 = *(const frag8*)(&KV[p][t * 2 + 0][lane * 8]);
            const frag8 k1 = *(const frag8*)(&KV[p][t * 2 + 1][lane * 8]);
#pragma unroll
            for (int g = 0; g < 2; ++g) {
                f32x4 s0 = __builtin_amdgcn_mfma_f32_16x16x32_bf16(k0, qf[g][0], z4, 0, 0, 0);
                S[g][t]  = __builtin_amdgcn_mfma_f32_16x16x32_bf16(k1, qf[g][1], s0, 0, 0, 0);
            }
        }
        if (c == NCHUNK - 1) {
            const int kb = c * 64 + quad * 4;   // k row index base for this lane
#pragma unroll
            for (int t = 0; t < 4; ++t)
#pragma unroll
                for (int j = 0; j < 4; ++j)
                    if (kb + t * 16 + j >= NT) {
                        S[0][t][j] = -1e30f;
                        S[1][t][j] = -1e30f;
                    }
        }

        // softmax: exp2 -> 3-op pack -> permlane assembly; both groups' pf
        frag8 pf[2][2];   // [g][s]
#pragma unroll
        for (int g = 0; g < 2; ++g) {
            unsigned lo[4], hi[4];
#pragma unroll
            for (int t = 0; t < 4; ++t) {
                lo[t] = pack_bf16_rh(fast_exp2(S[g][t][0]), fast_exp2(S[g][t][1]));
                hi[t] = pack_bf16_rh(fast_exp2(S[g][t][2]), fast_exp2(S[g][t][3]));
            }
#pragma unroll
            for (int s = 0; s < 2; ++s) {
                unsigned A = lo[2 * s], B = hi[2 * s];
                unsigned C = lo[2 * s + 1], D = hi[2 * s + 1];
                permlane32_swap(A, C);
                permlane32_swap(B, D);
                permlane16_swap(A, C);
                permlane16_swap(B, D);
                union { unsigned u[4]; frag8 f; } pu;
                pu.u[0] = A; pu.u[1] = B; pu.u[2] = C; pu.u[3] = D;
                pf[g][s] = pu.f;
                accL[g] = __builtin_amdgcn_mfma_f32_16x16x32_bf16(pf[g][s], ones, accL[g], 0, 0, 0);
            }
        }

        // O += P @ V ; vf read per (s,t), shared across both row-groups
#pragma unroll
        for (int s = 0; s < 2; ++s)
#pragma unroll
            for (int t = 0; t < 4; ++t) {
                const frag8 v = *(const frag8*)(&KV[p][8 + t * 2 + s][lane * 8]);
#pragma unroll
                for (int g = 0; g < 2; ++g)
                    accO[g][t] = __builtin_amdgcn_mfma_f32_16x16x32_bf16(pf[g][s], v, accO[g][t], 0, 0, 0);
            }

        // all waves done reading buf p before iter c+1 stages over buf p
        __asm__ volatile("s_waitcnt lgkmcnt(0)" ::: "memory");
        __builtin_amdgcn_s_barrier();
        __asm__ volatile("" ::: "memory");
        p ^= 1;
    }

    // write fp32 partials
    float* Op = O_part + (size_t)z * NT * DMODEL;
#pragma unroll
    for (int g = 0; g < 2; ++g)
#pragma unroll
        for (int j = 0; j < 4; ++j) {
            const int r = qbase + wave * 32 + g * 16 + quad * 4 + j;
            if (r < NT) {
#pragma unroll
                for (int t = 0; t < 4; ++t)
                    Op[(size_t)r * DMODEL + hoff + t * 16 + l16] = accO[g][t][j];
                if (l16 == 0)
                    l_part[((size_t)z * NHEAD + h) * NTP + r] = accL[g][j];
            }
        }
}

// ---------------------------------------------------------------------------
// Reduce kv-splits + per-head normalize + LayerNorm. grid = (NT), 192 thr.
// Each thread owns 4 consecutive dims (float4 loads; same head per quad).
// ---------------------------------------------------------------------------
__global__ __launch_bounds__(192) void reduce_ln_kernel(
    const float* __restrict__ O_part, const float* __restrict__ l_part,
    const float* __restrict__ g, const float* __restrict__ b,
    bf16* __restrict__ out, int nsplit) {
    const int n = blockIdx.x;
    const int tid = threadIdx.x;
    const int d0 = tid * 4;
    const int hh = d0 >> 6;

    float4 o = make_float4(0.f, 0.f, 0.f, 0.f);
    float lv = 0.f;
    for (int s = 0; s < nsplit; ++s) {
        float4 v = *(const float4*)(O_part + ((size_t)s * NT + n) * DMODEL + d0);
        o.x += v.x; o.y += v.y; o.z += v.z; o.w += v.w;
        lv += l_part[((size_t)s * NHEAD + hh) * NTP + n];
    }
    const float inv_l = 1.0f / lv;
    float vals[4] = {o.x * inv_l, o.y * inv_l, o.z * inv_l, o.w * inv_l};

    float s = vals[0] + vals[1] + vals[2] + vals[3];
    float s2 = vals[0] * vals[0] + vals[1] * vals[1] + vals[2] * vals[2] + vals[3] * vals[3];
#pragma unroll
    for (int off = 1; off < 64; off <<= 1) {
        s += __shfl_xor(s, off);
        s2 += __shfl_xor(s2, off);
    }
    __shared__ float ss[3], ss2[3];
    const int wave = tid >> 6, lane = tid & 63;
    if (lane == 0) { ss[wave] = s; ss2[wave] = s2; }
    __syncthreads();
    s = ss[0] + ss[1] + ss[2];
    s2 = ss2[0] + ss2[1] + ss2[2];
    const float mu = s * (1.0f / 768.0f);
    float var = s2 * (1.0f / 768.0f) - mu * mu;
    const float inv = rsqrtf(var + LN_EPS);

    unsigned short pk[4];
#pragma unroll
    for (int i = 0; i < 4; ++i) {
        const int d = d0 + i;
        const float v = (vals[i] - mu) * inv * g[d] + b[d];
        bf16 bb = __float2bfloat16(v);
        pk[i] = *(unsigned short*)&bb;
    }
    *(ushort4*)(out + (size_t)n * DMODEL + d0) = *(ushort4*)pk;
}

// ---------------------------------------------------------------------------
// Output projection v2: 128-row blocks, region-select. grid = (34, 12).
// Wave owns 32 rows as 2 groups sharing B-frags: 8 MFMA per 6 ds_read_b128.
// fp32 out.
// ---------------------------------------------------------------------------
__global__ __launch_bounds__(256, 2) void out_kernel(
    const bf16* __restrict__ Lb, const bf16* __restrict__ wo,
    const float* __restrict__ bo_p, const float* __restrict__ bo_d,
    float* __restrict__ out) {
    __shared__ bf16 As[128][32];
    __shared__ bf16 Bs[64][32];

    const int tid = threadIdx.x;
    const int wave = tid >> 6, lane = tid & 63;
    const int quad = lane >> 4, l16 = lane & 15;
    const int bx = blockIdx.x;
    const int is_det = bx >= 33;
    const int row0 = is_det ? NP : bx * 128;
    const int Mlim = is_det ? NT : NP;
    const int col0 = blockIdx.y * 64;
    const size_t nw = (size_t)DMODEL * DMODEL;
    const bf16* B = wo + (is_det ? nw : 0);
    const float* bias = is_det ? bo_d : bo_p;

    const f32x4 z4 = {0.f, 0.f, 0.f, 0.f};
    f32x4 acc[2][4];
#pragma unroll
    for (int gg = 0; gg < 2; ++gg)
#pragma unroll
        for (int t = 0; t < 4; ++t) acc[gg][t] = z4;

    // staging: As 128x32 (2 uint4/thread, same row), Bs 64x32 (1 uint4/thread)
    const int arow = tid >> 1;              // 0..127
    const int acol = (tid & 1) * 16;        // 0 or 16
    int a_r = row0 + arow;
    if (a_r >= Mlim) a_r = Mlim - 1;
    const bf16* ap = Lb + (size_t)a_r * DMODEL + acol;
    const int brow = tid >> 2;              // 0..63
    const int bcol = (tid & 3) * 8;
    const bf16* bp = B + (size_t)(col0 + brow) * DMODEL + bcol;

    uint4 areg0 = *(const uint4*)(ap);
    uint4 areg1 = *(const uint4*)(ap + 8);
    uint4 breg  = *(const uint4*)(bp);

    for (int k0 = 0; k0 < DMODEL; k0 += 32) {
        __syncthreads();
        *(uint4*)(&As[arow][acol]) = areg0;
        *(uint4*)(&As[arow][acol + 8]) = areg1;
        *(uint4*)(&Bs[brow][bcol]) = breg;
        if (k0 + 32 < DMODEL) {
            areg0 = *(const uint4*)(ap + k0 + 32);
            areg1 = *(const uint4*)(ap + k0 + 40);
            breg  = *(const uint4*)(bp + k0 + 32);
        }
        __asm__ volatile("s_waitcnt lgkmcnt(0)" ::: "memory");
        __builtin_amdgcn_s_barrier();
        __asm__ volatile("" ::: "memory");
        frag8 af[2], bfq[4];
#pragma unroll
        for (int gg = 0; gg < 2; ++gg)
            af[gg] = *(const frag8*)(&As[wave * 32 + gg * 16 + l16][quad * 8]);
#pragma unroll
        for (int t = 0; t < 4; ++t)
            bfq[t] = *(const frag8*)(&Bs[t * 16 + l16][quad * 8]);
#pragma unroll
        for (int gg = 0; gg < 2; ++gg)
#pragma unroll
            for (int t = 0; t < 4; ++t)
                acc[gg][t] = __builtin_amdgcn_mfma_f32_16x16x32_bf16(af[gg], bfq[t], acc[gg][t], 0, 0, 0);
        __asm__ volatile("" ::: "memory");
    }

#pragma unroll
    for (int gg = 0; gg < 2; ++gg) {
        const int rbase = row0 + wave * 32 + gg * 16 + quad * 4;
#pragma unroll
        for (int t = 0; t < 4; ++t) {
            const int c = col0 + t * 16 + l16;
            const float bv = bias[c];
#pragma unroll
            for (int j = 0; j < 4; ++j) {
                const int r = rbase + j;
                if (r < Mlim) out[(size_t)r * DMODEL + c] = acc[gg][t][j] + bv;
            }
        }
    }
}

// ---------------------------------------------------------------------------
extern "C" void kernel_launch(void* const* d_in, const int* in_sizes, int n_in,
                              void* d_out, int out_size, void* d_ws, size_t ws_size,
                              hipStream_t stream) {
    const float* x    = (const float*)d_in[0];
    const float* wq_p = (const float*)d_in[1];
    const float* wk_p = (const float*)d_in[2];
    const float* wv_p = (const float*)d_in[3];
    const float* wq_d = (const float*)d_in[4];
    const float* wk_d = (const float*)d_in[5];
    const float* wv_d = (const float*)d_in[6];
    const float* bq_p = (const float*)d_in[7];
    const float* bv_p = (const float*)d_in[8];
    const float* bq_d = (const float*)d_in[9];
    const float* bv_d = (const float*)d_in[10];
    const float* ln_g = (const float*)d_in[11];
    const float* ln_b = (const float*)d_in[12];
    const float* wo_p = (const float*)d_in[13];
    const float* bo_p = (const float*)d_in[14];
    const float* wo_d = (const float*)d_in[15];
    const float* bo_d = (const float*)d_in[16];
    float* out = (float*)d_out;

    const size_t nx  = (size_t)NT * DMODEL;       // 3,303,168
    const size_t nsw = (size_t)NHEAD * NCHUNK * CHUNKSZ;  // 3,342,336
    const size_t nw  = (size_t)DMODEL * DMODEL;   // 589,824

    // fixed region
    char* ws = (char*)d_ws;
    bf16* xb   = (bf16*)ws; ws += nx * 2;         // reused as Lb after qkv
    bf16* wqkv = (bf16*)ws; ws += 6 * nw * 2;
    bf16* wob  = (bf16*)ws; ws += 2 * nw * 2;
    bf16* Qb   = (bf16*)ws; ws += nx * 2;
    bf16* Ksw  = (bf16*)ws; ws += nsw * 2;
    bf16* Vsw  = (bf16*)ws; ws += nsw * 2;
    const size_t fixed = (size_t)(ws - (char*)d_ws);

    // per-split region: O_part (fp32 NT x 768) + l_part (fp32 12 x NTP)
    const size_t per_split = nx * 4 + (size_t)NHEAD * NTP * 4;
    int nsplit = 1;
    if (ws_size >= fixed + 4 * per_split) nsplit = 4;
    else if (ws_size >= fixed + 2 * per_split) nsplit = 2;
    const int cpb = NCHUNK / nsplit;              // 68 divisible by 1/2/4

    float* O_part = (float*)ws;
    float* l_part = (float*)(ws + (size_t)nsplit * nx * 4);
    bf16* Lb = xb;   // xb dead after qkv_kernel

    const int total = (int)(nx + 8 * nw);
    cast_all_kernel<<<dim3((total / 4 + 255) / 256), dim3(256), 0, stream>>>(
        x, wq_p, wk_p, wv_p, wq_d, wk_d, wv_d, wo_p, wo_d, xb, (int)nx, (int)nw, total);

    qkv_kernel<<<dim3(68, 12), dim3(256), 0, stream>>>(
        xb, wqkv, bq_p, bq_d, bv_p, bv_d, Qb, Ksw, Vsw);

    attn_kernel<<<dim3(NQB * NHEAD * nsplit), dim3(512), 0, stream>>>(
        Qb, Ksw, Vsw, O_part, l_part, cpb);

    reduce_ln_kernel<<<dim3(NT), dim3(192), 0, stream>>>(
        O_part, l_part, ln_g, ln_b, Lb, nsplit);

    out_kernel<<<dim3(34, 12), dim3(256), 0, stream>>>(Lb, wob, bo_p, bo_d, out);
}

// Round 8
// 246.108 us; speedup vs baseline: 2.2648x; 2.2648x over previous
//
#include <hip/hip_runtime.h>
#include <hip/hip_bf16.h>

// Problem constants
#define NT 4301   // total tokens
#define NP 4201   // patch tokens (use *_p weights)
#define NDET 100  // detection tokens (use *_d weights)
#define DMODEL 768
#define NHEAD 12
#define HD 64
#define LN_EPS 1e-5f
#define LOG2E 1.4426950408889634f
#define QSCALE (0.125f * LOG2E)   // attn scale folded with log2(e): softmax in exp2 domain
#define NTP 4352                  // padded token count (17*256 = 68*64)
#define NCHUNK 68                 // ceil(4301/64)
#define NQB 17                    // attn q-blocks (256 rows each)
#define FRAGSZ 512                // elems per frag blob: 64 lanes x 8 bf16
#define CHUNKSZ 4096              // elems per (head,chunk): 8 frags x 512

typedef __hip_bfloat16 bf16;
typedef __attribute__((ext_vector_type(4))) float f32x4;
typedef __attribute__((ext_vector_type(8))) short frag8;  // 8 bf16 in 4 VGPRs
typedef __attribute__((ext_vector_type(2))) unsigned int u32x2;

// permlane swap helpers (gfx950). Builtin returns {new_dst, new_src}; both used.
static __device__ __forceinline__ void permlane32_swap(unsigned& a, unsigned& b) {
#if __has_builtin(__builtin_amdgcn_permlane32_swap)
    u32x2 r = __builtin_amdgcn_permlane32_swap(a, b, false, false);
    a = r[0]; b = r[1];
#else
    asm("v_permlane32_swap_b32 %0, %1" : "+v"(a), "+v"(b));
#endif
}
static __device__ __forceinline__ void permlane16_swap(unsigned& a, unsigned& b) {
#if __has_builtin(__builtin_amdgcn_permlane16_swap)
    u32x2 r = __builtin_amdgcn_permlane16_swap(a, b, false, false);
    a = r[0]; b = r[1];
#else
    asm("v_permlane16_swap_b32 %0, %1" : "+v"(a), "+v"(b));
#endif
}

// native exp2 (no OCML guard code); v_exp_f32 handles the full f32 range.
static __device__ __forceinline__ float fast_exp2(float x) {
#if __has_builtin(__builtin_amdgcn_exp2f)
    return __builtin_amdgcn_exp2f(x);
#else
    return __builtin_exp2f(x);
#endif
}

// Pack two f32 -> bf16x2 (a -> low16, b -> high16) in 3 VALU ops, no asm.
// Round-half-up (add 0x8000 before truncate) ~= RNE for softmax P values;
// replaces the ~12-VALU software-RNE __float22bfloat162_rn.
static __device__ __forceinline__ unsigned pack_bf16_rh(float a, float b) {
    unsigned ua = __builtin_bit_cast(unsigned, a) + 0x8000u;
    unsigned ub = __builtin_bit_cast(unsigned, b) + 0x8000u;
    return __builtin_amdgcn_perm(ub, ua, 0x07060302u);
}

// async global->LDS, 16B per lane. LDS dest = wave-uniform base + lane*16
// (m104); global src is per-lane. Frag blobs are exactly 64 lanes x 16B.
static __device__ __forceinline__ void gload16(const bf16* g, bf16* l) {
    __builtin_amdgcn_global_load_lds(
        (const __attribute__((address_space(1))) void*)g,
        (__attribute__((address_space(3))) void*)l, 16, 0, 0);
}

// ---------------------------------------------------------------------------
// One fused cast: x + 8 weight matrices fp32->bf16 into contiguous ws region
// ---------------------------------------------------------------------------
__global__ __launch_bounds__(256) void cast_all_kernel(
    const float* __restrict__ x,
    const float* __restrict__ w0, const float* __restrict__ w1,
    const float* __restrict__ w2, const float* __restrict__ w3,
    const float* __restrict__ w4, const float* __restrict__ w5,
    const float* __restrict__ w6, const float* __restrict__ w7,
    bf16* __restrict__ dst, int nx, int nw, int total) {
    int i4 = (blockIdx.x * 256 + threadIdx.x) * 4;
    if (i4 >= total) return;
    const float* s;
    int off;
    if (i4 < nx) {
        s = x; off = i4;
    } else {
        int r = i4 - nx;
        int w = r / nw;
        off = r - w * nw;
        s = w0;
        if (w == 1) s = w1; else if (w == 2) s = w2; else if (w == 3) s = w3;
        else if (w == 4) s = w4; else if (w == 5) s = w5;
        else if (w == 6) s = w6; else if (w == 7) s = w7;
    }
    float4 v = *(const float4*)(s + off);
    bf16 o[4] = {__float2bfloat16(v.x), __float2bfloat16(v.y),
                 __float2bfloat16(v.z), __float2bfloat16(v.w)};
    *(ushort4*)(dst + i4) = *(ushort4*)o;
}

// ---------------------------------------------------------------------------
// Fused QKV v2: one block per (row-tile, head) computes Q, K, V together.
// grid = (68, 12). Outputs: Q*QSCALE row-major; K/V pre-swizzled frag order.
// ---------------------------------------------------------------------------
__global__ __launch_bounds__(256, 4) void qkv_kernel(
    const bf16* __restrict__ xb, const bf16* __restrict__ wbase,
    const float* __restrict__ bq_p, const float* __restrict__ bq_d,
    const float* __restrict__ bv_p, const float* __restrict__ bv_d,
    bf16* __restrict__ Qb, bf16* __restrict__ Ksw, bf16* __restrict__ Vsw) {
    __shared__ bf16 As[64][32];
    __shared__ bf16 Bs[192][32];   // rows 0-63: wq, 64-127: wk, 128-191: wv

    const int tid = threadIdx.x;
    const int wave = tid >> 6, lane = tid & 63;
    const int quad = lane >> 4, l16 = lane & 15;
    const int bx = blockIdx.x;
    const int h = blockIdx.y;
    const int is_det = bx >= 66;
    const int row0 = is_det ? NP + (bx - 66) * 64 : bx * 64;
    const int Mlim = is_det ? NT : NP;
    const int col0 = h * 64;
    const size_t nw = (size_t)DMODEL * DMODEL;
    const bf16* W = wbase + (is_det ? 3 * nw : 0);

    const f32x4 z4 = {0.f, 0.f, 0.f, 0.f};
    f32x4 acc[4][3];
#pragma unroll
    for (int r4 = 0; r4 < 4; ++r4)
#pragma unroll
        for (int f = 0; f < 3; ++f) acc[r4][f] = z4;

    const int srow = tid >> 2;          // 0..63
    const int scol8 = (tid & 3) * 8;    // 0,8,16,24
    int a_r = row0 + srow;
    if (a_r >= Mlim) a_r = Mlim - 1;
    const bf16* ap = xb + (size_t)a_r * DMODEL + scol8;
    const bf16* bp = W + (size_t)(col0 + srow) * DMODEL + scol8;

    uint4 areg  = *(const uint4*)(ap);
    uint4 breg0 = *(const uint4*)(bp);
    uint4 breg1 = *(const uint4*)(bp + nw);
    uint4 breg2 = *(const uint4*)(bp + 2 * nw);

    for (int k0 = 0; k0 < DMODEL; k0 += 32) {
        __syncthreads();
        *(uint4*)(&As[srow][scol8]) = areg;
        *(uint4*)(&Bs[srow][scol8]) = breg0;
        *(uint4*)(&Bs[64 + srow][scol8]) = breg1;
        *(uint4*)(&Bs[128 + srow][scol8]) = breg2;
        if (k0 + 32 < DMODEL) {
            areg  = *(const uint4*)(ap + k0 + 32);
            breg0 = *(const uint4*)(bp + k0 + 32);
            breg1 = *(const uint4*)(bp + nw + k0 + 32);
            breg2 = *(const uint4*)(bp + 2 * nw + k0 + 32);
        }
        __asm__ volatile("s_waitcnt lgkmcnt(0)" ::: "memory");
        __builtin_amdgcn_s_barrier();   // prefetch vmcnt stays in flight
        __asm__ volatile("" ::: "memory");
        frag8 af[4], bfr[3];
#pragma unroll
        for (int r4 = 0; r4 < 4; ++r4)
            af[r4] = *(const frag8*)(&As[r4 * 16 + l16][quad * 8]);
#pragma unroll
        for (int f = 0; f < 3; ++f)
            bfr[f] = *(const frag8*)(&Bs[wave * 48 + f * 16 + l16][quad * 8]);
#pragma unroll
        for (int r4 = 0; r4 < 4; ++r4)
#pragma unroll
            for (int f = 0; f < 3; ++f)
                acc[r4][f] = __builtin_amdgcn_mfma_f32_16x16x32_bf16(af[r4], bfr[f], acc[r4][f], 0, 0, 0);
        __asm__ volatile("" ::: "memory");
    }

    // epilogue: wave w covers logical cols [w*48, w*48+48); 16-col group oc=3w+f
#pragma unroll
    for (int f = 0; f < 3; ++f) {
        const int oc = 3 * wave + f;          // 0..11
        const int opi = oc >> 2;              // 0=Q 1=K 2=V
        const int cin = (oc & 3) * 16 + l16;  // head-dim 0..63
        const int c = col0 + cin;             // global dim
        float bv = 0.f, scale = 1.f;
        if (opi == 0) { bv = (is_det ? bq_d : bq_p)[c]; scale = QSCALE; }
        else if (opi == 2) { bv = (is_det ? bv_d : bv_p)[c]; }
#pragma unroll
        for (int r4 = 0; r4 < 4; ++r4) {
#pragma unroll
            for (int j = 0; j < 4; ++j) {
                const int r = row0 + r4 * 16 + quad * 4 + j;
                if (r >= Mlim) continue;
                const bf16 val = __float2bfloat16((acc[r4][f][j] + bv) * scale);
                if (opi == 0) {
                    Qb[(size_t)r * DMODEL + c] = val;
                } else if (opi == 1) {
                    const int cc = r >> 6, tf = (r >> 4) & 3, ln = r & 15;
                    const int s = cin >> 5, qd = (cin >> 3) & 3, je = cin & 7;
                    Ksw[((size_t)(h * NCHUNK + cc) * 8 + tf * 2 + s) * FRAGSZ +
                        (qd * 16 + ln) * 8 + je] = val;
                } else {
                    const int t = cin >> 4, le = cin & 15;
                    const int cc = r >> 6, rr = r & 63;
                    const int sv = rr >> 5, qv = (rr >> 3) & 3, je = rr & 7;
                    Vsw[((size_t)(h * NCHUNK + cc) * 8 + t * 2 + sv) * FRAGSZ +
                        (qv * 16 + le) * 8 + je] = val;
                }
            }
        }
    }
}

// ---------------------------------------------------------------------------
// Flash attention v15: 8-wave blocks (512 thr, 256 q-rows) with a VALID reg
// cap: __launch_bounds__(512, 4) -> 128 regs/wave (v14's (512,8)=64 spilled:
// WRITE_SIZE 52->933 MB, attn 397us). Triple-buffered K/V LDS, ONE barrier
// per chunk: reads of buf c%3 are safe because each wave's prior-iter
// ds_reads completed before it reached this barrier (MFMA data-dep), and
// stage writes for c+2 (-> buf (c-1)%3) are issued only after the barrier.
// Prefetch depth 2 chunks, counted vmcnt(2), never 0 mid-loop.
// ---------------------------------------------------------------------------
__global__ __launch_bounds__(512, 4) void attn_kernel(
    const bf16* __restrict__ Q, const bf16* __restrict__ Ksw,
    const bf16* __restrict__ Vsw, float* __restrict__ O_part,
    float* __restrict__ l_part, int cpb) {
    __shared__ bf16 KV[3][16][FRAGSZ];   // [buf][frag: 0-7 K, 8-15 V][lane*8]

    const int tid = threadIdx.x;
    const int wave = tid >> 6, lane = tid & 63;   // wave 0..7
    const int quad = lane >> 4, l16 = lane & 15;

    // decode (bx, h, z) from 1D id; XCD-chunked when blocks/XCD % NQB == 0
    int bx, h, z;
    {
        const int id = blockIdx.x;
        const int nblk = gridDim.x;
        const int per = nblk >> 3;
        if ((nblk & 7) == 0 && per % NQB == 0) {
            const int ppx = per / NQB;                // (h,z) pairs per XCD
            const int q = id >> 3;
            const int pair = (id & 7) * ppx + q / NQB;
            bx = q % NQB;
            h = pair % NHEAD; z = pair / NHEAD;
        } else {
            bx = id % NQB; h = (id / NQB) % NHEAD; z = id / (NQB * NHEAD);
        }
    }
    const int qbase = bx * 256;
    const int hoff = h * HD;
    const int c0 = z * cpb, c1 = c0 + cpb;

    frag8 ones;
#pragma unroll
    for (int j = 0; j < 8; ++j) ones[j] = (short)0x3F80;

    // Q fragments for 2 row-groups: rows qbase + wave*32 + g*16 + l16.
    frag8 qf[2][2];
#pragma unroll
    for (int g = 0; g < 2; ++g) {
        int qr = qbase + wave * 32 + g * 16 + l16;
        if (qr >= NT) qr = NT - 1;
#pragma unroll
        for (int s = 0; s < 2; ++s)
            qf[g][s] = *(const frag8*)(Q + (size_t)qr * DMODEL + hoff + s * 32 + quad * 8);
    }

    // staging: waves 0-3 -> K frags {2w,2w+1}; waves 4-7 -> V frags {2w',2w'+1}
    const bf16* kb0 = Ksw + (size_t)h * NCHUNK * CHUNKSZ + lane * 8;
    const bf16* vb0 = Vsw + (size_t)h * NCHUNK * CHUNKSZ + lane * 8;
    const bf16* sb = (wave < 4) ? kb0 : vb0;
    const int foff = (wave & 3) * 2;      // frag index within K or V blob
    const int fbase = 2 * wave;           // LDS frag row (0..15)

    const f32x4 z4 = {0.f, 0.f, 0.f, 0.f};
    f32x4 accO[2][4], accL[2];
#pragma unroll
    for (int g = 0; g < 2; ++g) {
        accL[g] = z4;
#pragma unroll
        for (int t = 0; t < 4; ++t) accO[g][t] = z4;
    }

    // drain qf loads so loop vmcnt counts only stage loads
    __asm__ volatile("s_waitcnt vmcnt(0)" ::: "memory");

    // prologue: stage chunk c0 -> buf0, c0+1 -> buf1 (2 gload_lds each/wave)
    {
        const bf16* s = sb + (size_t)c0 * CHUNKSZ + foff * FRAGSZ;
#pragma unroll
        for (int i = 0; i < 2; ++i)
            gload16(s + i * FRAGSZ, &KV[0][fbase + i][0]);
        if (c0 + 1 < c1) {
            const bf16* s1 = sb + (size_t)(c0 + 1) * CHUNKSZ + foff * FRAGSZ;
#pragma unroll
            for (int i = 0; i < 2; ++i)
                gload16(s1 + i * FRAGSZ, &KV[1][fbase + i][0]);
        }
    }

    int p = 0;                 // buffer holding chunk c
    for (int c = c0; c < c1; ++c) {
        // wait for chunk c's stage loads (c+1's 2 loads may stay in flight)
        if (c + 1 < c1) {
            __asm__ volatile("s_waitcnt vmcnt(2)" ::: "memory");
        } else {
            __asm__ volatile("s_waitcnt vmcnt(0)" ::: "memory");
        }
        __builtin_amdgcn_s_barrier();     // chunk c visible to all waves
        __asm__ volatile("" ::: "memory");

        // stage c+2 into buf (p+2)%3 (== (c-1)%3, safe after this barrier)
        if (c + 2 < c1) {
            const int q2 = (p + 2 >= 3) ? p - 1 : p + 2;
            const bf16* s = sb + (size_t)(c + 2) * CHUNKSZ + foff * FRAGSZ;
#pragma unroll
            for (int i = 0; i < 2; ++i)
                gload16(s + i * FRAGSZ, &KV[q2][fbase + i][0]);
        }

        // S^T = K @ Q^T; kf read per-t at point of use (8 live K VGPRs)
        f32x4 S[2][4];
#pragma unroll
        for (int t = 0; t < 4; ++t) {
            const frag8 k0 = *(const frag8*)(&KV[p][t * 2 + 0][lane * 8]);
            const frag8 k1 = *(const frag8*)(&KV[p][t * 2 + 1][lane * 8]);
#pragma unroll
            for (int g = 0; g < 2; ++g) {
                f32x4 s0 = __builtin_amdgcn_mfma_f32_16x16x32_bf16(k0, qf[g][0], z4, 0, 0, 0);
                S[g][t]  = __builtin_amdgcn_mfma_f32_16x16x32_bf16(k1, qf[g][1], s0, 0, 0, 0);
            }
        }
        if (c == NCHUNK - 1) {
            const int kb = c * 64 + quad * 4;   // k row index base for this lane
#pragma unroll
            for (int t = 0; t < 4; ++t)
#pragma unroll
                for (int j = 0; j < 4; ++j)
                    if (kb + t * 16 + j >= NT) {
                        S[0][t][j] = -1e30f;
                        S[1][t][j] = -1e30f;
                    }
        }

        // softmax: exp2 -> 3-op pack -> permlane assembly; both groups' pf
        frag8 pf[2][2];   // [g][s]
#pragma unroll
        for (int g = 0; g < 2; ++g) {
            unsigned lo[4], hi[4];
#pragma unroll
            for (int t = 0; t < 4; ++t) {
                lo[t] = pack_bf16_rh(fast_exp2(S[g][t][0]), fast_exp2(S[g][t][1]));
                hi[t] = pack_bf16_rh(fast_exp2(S[g][t][2]), fast_exp2(S[g][t][3]));
            }
#pragma unroll
            for (int s = 0; s < 2; ++s) {
                unsigned A = lo[2 * s], B = hi[2 * s];
                unsigned C = lo[2 * s + 1], D = hi[2 * s + 1];
                permlane32_swap(A, C);
                permlane32_swap(B, D);
                permlane16_swap(A, C);
                permlane16_swap(B, D);
                union { unsigned u[4]; frag8 f; } pu;
                pu.u[0] = A; pu.u[1] = B; pu.u[2] = C; pu.u[3] = D;
                pf[g][s] = pu.f;
                accL[g] = __builtin_amdgcn_mfma_f32_16x16x32_bf16(pf[g][s], ones, accL[g], 0, 0, 0);
            }
        }

        // O += P @ V ; vf read per (s,t), shared across both row-groups
#pragma unroll
        for (int s = 0; s < 2; ++s)
#pragma unroll
            for (int t = 0; t < 4; ++t) {
                const frag8 v = *(const frag8*)(&KV[p][8 + t * 2 + s][lane * 8]);
#pragma unroll
                for (int g = 0; g < 2; ++g)
                    accO[g][t] = __builtin_amdgcn_mfma_f32_16x16x32_bf16(pf[g][s], v, accO[g][t], 0, 0, 0);
            }

        p = (p + 1 >= 3) ? 0 : p + 1;
    }

    // write fp32 partials
    float* Op = O_part + (size_t)z * NT * DMODEL;
#pragma unroll
    for (int g = 0; g < 2; ++g)
#pragma unroll
        for (int j = 0; j < 4; ++j) {
            const int r = qbase + wave * 32 + g * 16 + quad * 4 + j;
            if (r < NT) {
#pragma unroll
                for (int t = 0; t < 4; ++t)
                    Op[(size_t)r * DMODEL + hoff + t * 16 + l16] = accO[g][t][j];
                if (l16 == 0)
                    l_part[((size_t)z * NHEAD + h) * NTP + r] = accL[g][j];
            }
        }
}

// ---------------------------------------------------------------------------
// Reduce kv-splits + per-head normalize + LayerNorm. grid = (NT), 192 thr.
// Each thread owns 4 consecutive dims (float4 loads; same head per quad).
// ---------------------------------------------------------------------------
__global__ __launch_bounds__(192) void reduce_ln_kernel(
    const float* __restrict__ O_part, const float* __restrict__ l_part,
    const float* __restrict__ g, const float* __restrict__ b,
    bf16* __restrict__ out, int nsplit) {
    const int n = blockIdx.x;
    const int tid = threadIdx.x;
    const int d0 = tid * 4;
    const int hh = d0 >> 6;

    float4 o = make_float4(0.f, 0.f, 0.f, 0.f);
    float lv = 0.f;
    for (int s = 0; s < nsplit; ++s) {
        float4 v = *(const float4*)(O_part + ((size_t)s * NT + n) * DMODEL + d0);
        o.x += v.x; o.y += v.y; o.z += v.z; o.w += v.w;
        lv += l_part[((size_t)s * NHEAD + hh) * NTP + n];
    }
    const float inv_l = 1.0f / lv;
    float vals[4] = {o.x * inv_l, o.y * inv_l, o.z * inv_l, o.w * inv_l};

    float s = vals[0] + vals[1] + vals[2] + vals[3];
    float s2 = vals[0] * vals[0] + vals[1] * vals[1] + vals[2] * vals[2] + vals[3] * vals[3];
#pragma unroll
    for (int off = 1; off < 64; off <<= 1) {
        s += __shfl_xor(s, off);
        s2 += __shfl_xor(s2, off);
    }
    __shared__ float ss[3], ss2[3];
    const int wave = tid >> 6, lane = tid & 63;
    if (lane == 0) { ss[wave] = s; ss2[wave] = s2; }
    __syncthreads();
    s = ss[0] + ss[1] + ss[2];
    s2 = ss2[0] + ss2[1] + ss2[2];
    const float mu = s * (1.0f / 768.0f);
    float var = s2 * (1.0f / 768.0f) - mu * mu;
    const float inv = rsqrtf(var + LN_EPS);

    unsigned short pk[4];
#pragma unroll
    for (int i = 0; i < 4; ++i) {
        const int d = d0 + i;
        const float v = (vals[i] - mu) * inv * g[d] + b[d];
        bf16 bb = __float2bfloat16(v);
        pk[i] = *(unsigned short*)&bb;
    }
    *(ushort4*)(out + (size_t)n * DMODEL + d0) = *(ushort4*)pk;
}

// ---------------------------------------------------------------------------
// Output projection v2: 128-row blocks, region-select. grid = (34, 12).
// Wave owns 32 rows as 2 groups sharing B-frags: 8 MFMA per 6 ds_read_b128.
// fp32 out.
// ---------------------------------------------------------------------------
__global__ __launch_bounds__(256, 2) void out_kernel(
    const bf16* __restrict__ Lb, const bf16* __restrict__ wo,
    const float* __restrict__ bo_p, const float* __restrict__ bo_d,
    float* __restrict__ out) {
    __shared__ bf16 As[128][32];
    __shared__ bf16 Bs[64][32];

    const int tid = threadIdx.x;
    const int wave = tid >> 6, lane = tid & 63;
    const int quad = lane >> 4, l16 = lane & 15;
    const int bx = blockIdx.x;
    const int is_det = bx >= 33;
    const int row0 = is_det ? NP : bx * 128;
    const int Mlim = is_det ? NT : NP;
    const int col0 = blockIdx.y * 64;
    const size_t nw = (size_t)DMODEL * DMODEL;
    const bf16* B = wo + (is_det ? nw : 0);
    const float* bias = is_det ? bo_d : bo_p;

    const f32x4 z4 = {0.f, 0.f, 0.f, 0.f};
    f32x4 acc[2][4];
#pragma unroll
    for (int gg = 0; gg < 2; ++gg)
#pragma unroll
        for (int t = 0; t < 4; ++t) acc[gg][t] = z4;

    // staging: As 128x32 (2 uint4/thread, same row), Bs 64x32 (1 uint4/thread)
    const int arow = tid >> 1;              // 0..127
    const int acol = (tid & 1) * 16;        // 0 or 16
    int a_r = row0 + arow;
    if (a_r >= Mlim) a_r = Mlim - 1;
    const bf16* ap = Lb + (size_t)a_r * DMODEL + acol;
    const int brow = tid >> 2;              // 0..63
    const int bcol = (tid & 3) * 8;
    const bf16* bp = B + (size_t)(col0 + brow) * DMODEL + bcol;

    uint4 areg0 = *(const uint4*)(ap);
    uint4 areg1 = *(const uint4*)(ap + 8);
    uint4 breg  = *(const uint4*)(bp);

    for (int k0 = 0; k0 < DMODEL; k0 += 32) {
        __syncthreads();
        *(uint4*)(&As[arow][acol]) = areg0;
        *(uint4*)(&As[arow][acol + 8]) = areg1;
        *(uint4*)(&Bs[brow][bcol]) = breg;
        if (k0 + 32 < DMODEL) {
            areg0 = *(const uint4*)(ap + k0 + 32);
            areg1 = *(const uint4*)(ap + k0 + 40);
            breg  = *(const uint4*)(bp + k0 + 32);
        }
        __asm__ volatile("s_waitcnt lgkmcnt(0)" ::: "memory");
        __builtin_amdgcn_s_barrier();
        __asm__ volatile("" ::: "memory");
        frag8 af[2], bfq[4];
#pragma unroll
        for (int gg = 0; gg < 2; ++gg)
            af[gg] = *(const frag8*)(&As[wave * 32 + gg * 16 + l16][quad * 8]);
#pragma unroll
        for (int t = 0; t < 4; ++t)
            bfq[t] = *(const frag8*)(&Bs[t * 16 + l16][quad * 8]);
#pragma unroll
        for (int gg = 0; gg < 2; ++gg)
#pragma unroll
            for (int t = 0; t < 4; ++t)
                acc[gg][t] = __builtin_amdgcn_mfma_f32_16x16x32_bf16(af[gg], bfq[t], acc[gg][t], 0, 0, 0);
        __asm__ volatile("" ::: "memory");
    }

#pragma unroll
    for (int gg = 0; gg < 2; ++gg) {
        const int rbase = row0 + wave * 32 + gg * 16 + quad * 4;
#pragma unroll
        for (int t = 0; t < 4; ++t) {
            const int c = col0 + t * 16 + l16;
            const float bv = bias[c];
#pragma unroll
            for (int j = 0; j < 4; ++j) {
                const int r = rbase + j;
                if (r < Mlim) out[(size_t)r * DMODEL + c] = acc[gg][t][j] + bv;
            }
        }
    }
}

// ---------------------------------------------------------------------------
extern "C" void kernel_launch(void* const* d_in, const int* in_sizes, int n_in,
                              void* d_out, int out_size, void* d_ws, size_t ws_size,
                              hipStream_t stream) {
    const float* x    = (const float*)d_in[0];
    const float* wq_p = (const float*)d_in[1];
    const float* wk_p = (const float*)d_in[2];
    const float* wv_p = (const float*)d_in[3];
    const float* wq_d = (const float*)d_in[4];
    const float* wk_d = (const float*)d_in[5];
    const float* wv_d = (const float*)d_in[6];
    const float* bq_p = (const float*)d_in[7];
    const float* bv_p = (const float*)d_in[8];
    const float* bq_d = (const float*)d_in[9];
    const float* bv_d = (const float*)d_in[10];
    const float* ln_g = (const float*)d_in[11];
    const float* ln_b = (const float*)d_in[12];
    const float* wo_p = (const float*)d_in[13];
    const float* bo_p = (const float*)d_in[14];
    const float* wo_d = (const float*)d_in[15];
    const float* bo_d = (const float*)d_in[16];
    float* out = (float*)d_out;

    const size_t nx  = (size_t)NT * DMODEL;       // 3,303,168
    const size_t nsw = (size_t)NHEAD * NCHUNK * CHUNKSZ;  // 3,342,336
    const size_t nw  = (size_t)DMODEL * DMODEL;   // 589,824

    // fixed region
    char* ws = (char*)d_ws;
    bf16* xb   = (bf16*)ws; ws += nx * 2;         // reused as Lb after qkv
    bf16* wqkv = (bf16*)ws; ws += 6 * nw * 2;
    bf16* wob  = (bf16*)ws; ws += 2 * nw * 2;
    bf16* Qb   = (bf16*)ws; ws += nx * 2;
    bf16* Ksw  = (bf16*)ws; ws += nsw * 2;
    bf16* Vsw  = (bf16*)ws; ws += nsw * 2;
    const size_t fixed = (size_t)(ws - (char*)d_ws);

    // per-split region: O_part (fp32 NT x 768) + l_part (fp32 12 x NTP)
    const size_t per_split = nx * 4 + (size_t)NHEAD * NTP * 4;
    int nsplit = 1;
    if (ws_size >= fixed + 4 * per_split) nsplit = 4;
    else if (ws_size >= fixed + 2 * per_split) nsplit = 2;
    const int cpb = NCHUNK / nsplit;              // 68 divisible by 1/2/4

    float* O_part = (float*)ws;
    float* l_part = (float*)(ws + (size_t)nsplit * nx * 4);
    bf16* Lb = xb;   // xb dead after qkv_kernel

    const int total = (int)(nx + 8 * nw);
    cast_all_kernel<<<dim3((total / 4 + 255) / 256), dim3(256), 0, stream>>>(
        x, wq_p, wk_p, wv_p, wq_d, wk_d, wv_d, wo_p, wo_d, xb, (int)nx, (int)nw, total);

    qkv_kernel<<<dim3(68, 12), dim3(256), 0, stream>>>(
        xb, wqkv, bq_p, bq_d, bv_p, bv_d, Qb, Ksw, Vsw);

    attn_kernel<<<dim3(NQB * NHEAD * nsplit), dim3(512), 0, stream>>>(
        Qb, Ksw, Vsw, O_part, l_part, cpb);

    reduce_ln_kernel<<<dim3(NT), dim3(192), 0, stream>>>(
        O_part, l_part, ln_g, ln_b, Lb, nsplit);

    out_kernel<<<dim3(34, 12), dim3(256), 0, stream>>>(Lb, wob, bo_p, bo_d, out);
}

// Round 9
// 232.748 us; speedup vs baseline: 2.3948x; 1.0574x over previous
//
#include <hip/hip_runtime.h>
#include <hip/hip_bf16.h>

// Problem constants
#define NT 4301   // total tokens
#define NP 4201   // patch tokens (use *_p weights)
#define NDET 100  // detection tokens (use *_d weights)
#define DMODEL 768
#define NHEAD 12
#define HD 64
#define LN_EPS 1e-5f
#define LOG2E 1.4426950408889634f
#define QSCALE (0.125f * LOG2E)   // attn scale folded with log2(e): softmax in exp2 domain
#define NTP 4352                  // padded token count (34*128 = 68*64)
#define NCHUNK 68                 // ceil(4301/64)
#define FRAGSZ 512                // elems per frag blob: 64 lanes x 8 bf16
#define CHUNKSZ 4096              // elems per (head,chunk): 8 frags x 512

typedef __hip_bfloat16 bf16;
typedef __attribute__((ext_vector_type(4))) float f32x4;
typedef __attribute__((ext_vector_type(8))) short frag8;  // 8 bf16 in 4 VGPRs
typedef __attribute__((ext_vector_type(2))) unsigned int u32x2;

// permlane swap helpers (gfx950). Builtin returns {new_dst, new_src}; both used.
static __device__ __forceinline__ void permlane32_swap(unsigned& a, unsigned& b) {
#if __has_builtin(__builtin_amdgcn_permlane32_swap)
    u32x2 r = __builtin_amdgcn_permlane32_swap(a, b, false, false);
    a = r[0]; b = r[1];
#else
    asm("v_permlane32_swap_b32 %0, %1" : "+v"(a), "+v"(b));
#endif
}
static __device__ __forceinline__ void permlane16_swap(unsigned& a, unsigned& b) {
#if __has_builtin(__builtin_amdgcn_permlane16_swap)
    u32x2 r = __builtin_amdgcn_permlane16_swap(a, b, false, false);
    a = r[0]; b = r[1];
#else
    asm("v_permlane16_swap_b32 %0, %1" : "+v"(a), "+v"(b));
#endif
}

// native exp2 (no OCML guard code); v_exp_f32 handles the full f32 range.
static __device__ __forceinline__ float fast_exp2(float x) {
#if __has_builtin(__builtin_amdgcn_exp2f)
    return __builtin_amdgcn_exp2f(x);
#else
    return __builtin_exp2f(x);
#endif
}

// Pack two f32 -> bf16x2 (a -> low16, b -> high16) in ONE v_perm_b32.
// Truncation (no round-to-nearest): softmax divides sum(P*V) by sum(P), so
// the uniform downward bias ~cancels; saves 2 VALU adds per pair vs
// round-half-up (v13 used +0x8000).
static __device__ __forceinline__ unsigned pack_bf16_tr(float a, float b) {
    return __builtin_amdgcn_perm(__builtin_bit_cast(unsigned, b),
                                 __builtin_bit_cast(unsigned, a), 0x07060302u);
}

// async global->LDS, 16B per lane. LDS dest = wave-uniform base + lane*16
// (m104); global src is per-lane. Frag blobs are exactly 64 lanes x 16B.
static __device__ __forceinline__ void gload16(const bf16* g, bf16* l) {
    __builtin_amdgcn_global_load_lds(
        (const __attribute__((address_space(1))) void*)g,
        (__attribute__((address_space(3))) void*)l, 16, 0, 0);
}

// ---------------------------------------------------------------------------
// One fused cast: x + 8 weight matrices fp32->bf16 into contiguous ws region
// ---------------------------------------------------------------------------
__global__ __launch_bounds__(256) void cast_all_kernel(
    const float* __restrict__ x,
    const float* __restrict__ w0, const float* __restrict__ w1,
    const float* __restrict__ w2, const float* __restrict__ w3,
    const float* __restrict__ w4, const float* __restrict__ w5,
    const float* __restrict__ w6, const float* __restrict__ w7,
    bf16* __restrict__ dst, int nx, int nw, int total) {
    int i4 = (blockIdx.x * 256 + threadIdx.x) * 4;
    if (i4 >= total) return;
    const float* s;
    int off;
    if (i4 < nx) {
        s = x; off = i4;
    } else {
        int r = i4 - nx;
        int w = r / nw;
        off = r - w * nw;
        s = w0;
        if (w == 1) s = w1; else if (w == 2) s = w2; else if (w == 3) s = w3;
        else if (w == 4) s = w4; else if (w == 5) s = w5;
        else if (w == 6) s = w6; else if (w == 7) s = w7;
    }
    float4 v = *(const float4*)(s + off);
    bf16 o[4] = {__float2bfloat16(v.x), __float2bfloat16(v.y),
                 __float2bfloat16(v.z), __float2bfloat16(v.w)};
    *(ushort4*)(dst + i4) = *(ushort4*)o;
}

// ---------------------------------------------------------------------------
// Fused QKV v2: one block per (row-tile, head) computes Q, K, V together.
// grid = (68, 12). Outputs: Q*QSCALE row-major; K/V pre-swizzled frag order.
// ---------------------------------------------------------------------------
__global__ __launch_bounds__(256, 4) void qkv_kernel(
    const bf16* __restrict__ xb, const bf16* __restrict__ wbase,
    const float* __restrict__ bq_p, const float* __restrict__ bq_d,
    const float* __restrict__ bv_p, const float* __restrict__ bv_d,
    bf16* __restrict__ Qb, bf16* __restrict__ Ksw, bf16* __restrict__ Vsw) {
    __shared__ bf16 As[64][32];
    __shared__ bf16 Bs[192][32];   // rows 0-63: wq, 64-127: wk, 128-191: wv

    const int tid = threadIdx.x;
    const int wave = tid >> 6, lane = tid & 63;
    const int quad = lane >> 4, l16 = lane & 15;
    const int bx = blockIdx.x;
    const int h = blockIdx.y;
    const int is_det = bx >= 66;
    const int row0 = is_det ? NP + (bx - 66) * 64 : bx * 64;
    const int Mlim = is_det ? NT : NP;
    const int col0 = h * 64;
    const size_t nw = (size_t)DMODEL * DMODEL;
    const bf16* W = wbase + (is_det ? 3 * nw : 0);

    const f32x4 z4 = {0.f, 0.f, 0.f, 0.f};
    f32x4 acc[4][3];
#pragma unroll
    for (int r4 = 0; r4 < 4; ++r4)
#pragma unroll
        for (int f = 0; f < 3; ++f) acc[r4][f] = z4;

    const int srow = tid >> 2;          // 0..63
    const int scol8 = (tid & 3) * 8;    // 0,8,16,24
    int a_r = row0 + srow;
    if (a_r >= Mlim) a_r = Mlim - 1;
    const bf16* ap = xb + (size_t)a_r * DMODEL + scol8;
    const bf16* bp = W + (size_t)(col0 + srow) * DMODEL + scol8;

    uint4 areg  = *(const uint4*)(ap);
    uint4 breg0 = *(const uint4*)(bp);
    uint4 breg1 = *(const uint4*)(bp + nw);
    uint4 breg2 = *(const uint4*)(bp + 2 * nw);

    for (int k0 = 0; k0 < DMODEL; k0 += 32) {
        __syncthreads();
        *(uint4*)(&As[srow][scol8]) = areg;
        *(uint4*)(&Bs[srow][scol8]) = breg0;
        *(uint4*)(&Bs[64 + srow][scol8]) = breg1;
        *(uint4*)(&Bs[128 + srow][scol8]) = breg2;
        if (k0 + 32 < DMODEL) {
            areg  = *(const uint4*)(ap + k0 + 32);
            breg0 = *(const uint4*)(bp + k0 + 32);
            breg1 = *(const uint4*)(bp + nw + k0 + 32);
            breg2 = *(const uint4*)(bp + 2 * nw + k0 + 32);
        }
        __asm__ volatile("s_waitcnt lgkmcnt(0)" ::: "memory");
        __builtin_amdgcn_s_barrier();   // prefetch vmcnt stays in flight
        __asm__ volatile("" ::: "memory");
        frag8 af[4], bfr[3];
#pragma unroll
        for (int r4 = 0; r4 < 4; ++r4)
            af[r4] = *(const frag8*)(&As[r4 * 16 + l16][quad * 8]);
#pragma unroll
        for (int f = 0; f < 3; ++f)
            bfr[f] = *(const frag8*)(&Bs[wave * 48 + f * 16 + l16][quad * 8]);
#pragma unroll
        for (int r4 = 0; r4 < 4; ++r4)
#pragma unroll
            for (int f = 0; f < 3; ++f)
                acc[r4][f] = __builtin_amdgcn_mfma_f32_16x16x32_bf16(af[r4], bfr[f], acc[r4][f], 0, 0, 0);
        __asm__ volatile("" ::: "memory");
    }

    // epilogue: wave w covers logical cols [w*48, w*48+48); 16-col group oc=3w+f
#pragma unroll
    for (int f = 0; f < 3; ++f) {
        const int oc = 3 * wave + f;          // 0..11
        const int opi = oc >> 2;              // 0=Q 1=K 2=V
        const int cin = (oc & 3) * 16 + l16;  // head-dim 0..63
        const int c = col0 + cin;             // global dim
        float bv = 0.f, scale = 1.f;
        if (opi == 0) { bv = (is_det ? bq_d : bq_p)[c]; scale = QSCALE; }
        else if (opi == 2) { bv = (is_det ? bv_d : bv_p)[c]; }
#pragma unroll
        for (int r4 = 0; r4 < 4; ++r4) {
#pragma unroll
            for (int j = 0; j < 4; ++j) {
                const int r = row0 + r4 * 16 + quad * 4 + j;
                if (r >= Mlim) continue;
                const bf16 val = __float2bfloat16((acc[r4][f][j] + bv) * scale);
                if (opi == 0) {
                    Qb[(size_t)r * DMODEL + c] = val;
                } else if (opi == 1) {
                    const int cc = r >> 6, tf = (r >> 4) & 3, ln = r & 15;
                    const int s = cin >> 5, qd = (cin >> 3) & 3, je = cin & 7;
                    Ksw[((size_t)(h * NCHUNK + cc) * 8 + tf * 2 + s) * FRAGSZ +
                        (qd * 16 + ln) * 8 + je] = val;
                } else {
                    const int t = cin >> 4, le = cin & 15;
                    const int cc = r >> 6, rr = r & 63;
                    const int sv = rr >> 5, qv = (rr >> 3) & 3, je = rr & 7;
                    Vsw[((size_t)(h * NCHUNK + cc) * 8 + t * 2 + sv) * FRAGSZ +
                        (qv * 16 + le) * 8 + je] = val;
                }
            }
        }
    }
}

// ---------------------------------------------------------------------------
// Flash attention v16: v13 base (4-wave/256-thr blocks, 128 q-rows, 32 KB
// double-buffered K/V, register diet, launch_bounds(256,4)) with:
//  (a) T3 minimum 2-phase loop — ONE barrier per chunk: {stage(c+1 -> buf^1);
//      compute(c); vmcnt(0); barrier}. WAR-safe: reads of buf^1 (chunk c-1)
//      were consumed by that iteration's MFMAs before its end-barrier; the
//      end-of-iter vmcnt(0) is cheap (loads had a full compute to land).
//  (b) truncating bf16 pack (1 v_perm, no +0x8000 rounding) — softmax
//      ratio cancels the bias; saves 32 VALU/chunk.
// ---------------------------------------------------------------------------
__global__ __launch_bounds__(256, 4) void attn_kernel(
    const bf16* __restrict__ Q, const bf16* __restrict__ Ksw,
    const bf16* __restrict__ Vsw, float* __restrict__ O_part,
    float* __restrict__ l_part, int cpb) {
    __shared__ bf16 KV[2][16][FRAGSZ];   // [buf][frag: 0-7 K, 8-15 V][lane*8]

    const int tid = threadIdx.x;
    const int wave = tid >> 6, lane = tid & 63;
    const int quad = lane >> 4, l16 = lane & 15;

    // decode (bx, h, z) from 1D id; XCD-chunked when blocks/XCD % 34 == 0
    int bx, h, z;
    {
        const int id = blockIdx.x;
        const int nblk = gridDim.x;
        const int per = nblk >> 3;
        if ((nblk & 7) == 0 && per % 34 == 0) {
            const int ppx = per / 34;                 // (h,z) pairs per XCD
            const int q = id >> 3;
            const int pair = (id & 7) * ppx + q / 34;
            bx = q % 34;
            h = pair % NHEAD; z = pair / NHEAD;
        } else {
            bx = id % 34; h = (id / 34) % NHEAD; z = id / (34 * NHEAD);
        }
    }
    const int qbase = bx * 128;
    const int hoff = h * HD;
    const int c0 = z * cpb, c1 = c0 + cpb;

    frag8 ones;
#pragma unroll
    for (int j = 0; j < 8; ++j) ones[j] = (short)0x3F80;

    // Q fragments for 2 row-groups: rows qbase + wave*32 + g*16 + l16.
    frag8 qf[2][2];
#pragma unroll
    for (int g = 0; g < 2; ++g) {
        int qr = qbase + wave * 32 + g * 16 + l16;
        if (qr >= NT) qr = NT - 1;
#pragma unroll
        for (int s = 0; s < 2; ++s)
            qf[g][s] = *(const frag8*)(Q + (size_t)qr * DMODEL + hoff + s * 32 + quad * 8);
    }

    // staging: wave 0/1 -> K frags 0-3/4-7, wave 2/3 -> V frags 0-3/4-7.
    const bf16* kb0 = Ksw + (size_t)h * NCHUNK * CHUNKSZ + lane * 8;
    const bf16* vb0 = Vsw + (size_t)h * NCHUNK * CHUNKSZ + lane * 8;
    const bf16* sb = (wave < 2) ? kb0 : vb0;
    const int foff = (wave & 1) * 4;      // frag index within K or V blob
    const int fbase = 4 * wave;           // LDS frag row

    const f32x4 z4 = {0.f, 0.f, 0.f, 0.f};
    f32x4 accO[2][4], accL[2];
#pragma unroll
    for (int g = 0; g < 2; ++g) {
        accL[g] = z4;
#pragma unroll
        for (int t = 0; t < 4; ++t) accO[g][t] = z4;
    }

    // prologue: stage chunk c0 into buffer 0, drain, sync
    {
        const bf16* s = sb + (size_t)c0 * CHUNKSZ + foff * FRAGSZ;
#pragma unroll
        for (int i = 0; i < 4; ++i)
            gload16(s + i * FRAGSZ, &KV[0][fbase + i][0]);
    }
    __asm__ volatile("s_waitcnt vmcnt(0)" ::: "memory");
    __builtin_amdgcn_s_barrier();
    __asm__ volatile("" ::: "memory");

    int p = 0;
    for (int c = c0; c < c1; ++c) {
        // stage next chunk into the other buffer; flight hidden under compute
        if (c + 1 < c1) {
            const bf16* s = sb + (size_t)(c + 1) * CHUNKSZ + foff * FRAGSZ;
#pragma unroll
            for (int i = 0; i < 4; ++i)
                gload16(s + i * FRAGSZ, &KV[p ^ 1][fbase + i][0]);
        }

        // S^T = K @ Q^T; kf read per-t at point of use (8 live K VGPRs)
        f32x4 S[2][4];
#pragma unroll
        for (int t = 0; t < 4; ++t) {
            const frag8 k0 = *(const frag8*)(&KV[p][t * 2 + 0][lane * 8]);
            const frag8 k1 = *(const frag8*)(&KV[p][t * 2 + 1][lane * 8]);
#pragma unroll
            for (int g = 0; g < 2; ++g) {
                f32x4 s0 = __builtin_amdgcn_mfma_f32_16x16x32_bf16(k0, qf[g][0], z4, 0, 0, 0);
                S[g][t]  = __builtin_amdgcn_mfma_f32_16x16x32_bf16(k1, qf[g][1], s0, 0, 0, 0);
            }
        }
        if (c == NCHUNK - 1) {
            const int kb = c * 64 + quad * 4;   // k row index base for this lane
#pragma unroll
            for (int t = 0; t < 4; ++t)
#pragma unroll
                for (int j = 0; j < 4; ++j)
                    if (kb + t * 16 + j >= NT) {
                        S[0][t][j] = -1e30f;
                        S[1][t][j] = -1e30f;
                    }
        }

        // softmax: exp2 -> 1-op truncating pack -> permlane assembly
        frag8 pf[2][2];   // [g][s]
#pragma unroll
        for (int g = 0; g < 2; ++g) {
            unsigned lo[4], hi[4];
#pragma unroll
            for (int t = 0; t < 4; ++t) {
                lo[t] = pack_bf16_tr(fast_exp2(S[g][t][0]), fast_exp2(S[g][t][1]));
                hi[t] = pack_bf16_tr(fast_exp2(S[g][t][2]), fast_exp2(S[g][t][3]));
            }
#pragma unroll
            for (int s = 0; s < 2; ++s) {
                unsigned A = lo[2 * s], B = hi[2 * s];
                unsigned C = lo[2 * s + 1], D = hi[2 * s + 1];
                permlane32_swap(A, C);
                permlane32_swap(B, D);
                permlane16_swap(A, C);
                permlane16_swap(B, D);
                union { unsigned u[4]; frag8 f; } pu;
                pu.u[0] = A; pu.u[1] = B; pu.u[2] = C; pu.u[3] = D;
                pf[g][s] = pu.f;
                accL[g] = __builtin_amdgcn_mfma_f32_16x16x32_bf16(pf[g][s], ones, accL[g], 0, 0, 0);
            }
        }

        // O += P @ V ; vf read per (s,t), shared across both row-groups
#pragma unroll
        for (int s = 0; s < 2; ++s)
#pragma unroll
            for (int t = 0; t < 4; ++t) {
                const frag8 v = *(const frag8*)(&KV[p][8 + t * 2 + s][lane * 8]);
#pragma unroll
                for (int g = 0; g < 2; ++g)
                    accO[g][t] = __builtin_amdgcn_mfma_f32_16x16x32_bf16(pf[g][s], v, accO[g][t], 0, 0, 0);
            }

        // single barrier per chunk: stage writes landed (vmcnt 0, hidden
        // under the compute above) and every wave is done reading buf p.
        __asm__ volatile("s_waitcnt vmcnt(0)" ::: "memory");
        __builtin_amdgcn_s_barrier();
        __asm__ volatile("" ::: "memory");
        p ^= 1;
    }

    // write fp32 partials
    float* Op = O_part + (size_t)z * NT * DMODEL;
#pragma unroll
    for (int g = 0; g < 2; ++g)
#pragma unroll
        for (int j = 0; j < 4; ++j) {
            const int r = qbase + wave * 32 + g * 16 + quad * 4 + j;
            if (r < NT) {
#pragma unroll
                for (int t = 0; t < 4; ++t)
                    Op[(size_t)r * DMODEL + hoff + t * 16 + l16] = accO[g][t][j];
                if (l16 == 0)
                    l_part[((size_t)z * NHEAD + h) * NTP + r] = accL[g][j];
            }
        }
}

// ---------------------------------------------------------------------------
// Reduce kv-splits + per-head normalize + LayerNorm. grid = (NT), 192 thr.
// Each thread owns 4 consecutive dims (float4 loads; same head per quad).
// ---------------------------------------------------------------------------
__global__ __launch_bounds__(192) void reduce_ln_kernel(
    const float* __restrict__ O_part, const float* __restrict__ l_part,
    const float* __restrict__ g, const float* __restrict__ b,
    bf16* __restrict__ out, int nsplit) {
    const int n = blockIdx.x;
    const int tid = threadIdx.x;
    const int d0 = tid * 4;
    const int hh = d0 >> 6;

    float4 o = make_float4(0.f, 0.f, 0.f, 0.f);
    float lv = 0.f;
    for (int s = 0; s < nsplit; ++s) {
        float4 v = *(const float4*)(O_part + ((size_t)s * NT + n) * DMODEL + d0);
        o.x += v.x; o.y += v.y; o.z += v.z; o.w += v.w;
        lv += l_part[((size_t)s * NHEAD + hh) * NTP + n];
    }
    const float inv_l = 1.0f / lv;
    float vals[4] = {o.x * inv_l, o.y * inv_l, o.z * inv_l, o.w * inv_l};

    float s = vals[0] + vals[1] + vals[2] + vals[3];
    float s2 = vals[0] * vals[0] + vals[1] * vals[1] + vals[2] * vals[2] + vals[3] * vals[3];
#pragma unroll
    for (int off = 1; off < 64; off <<= 1) {
        s += __shfl_xor(s, off);
        s2 += __shfl_xor(s2, off);
    }
    __shared__ float ss[3], ss2[3];
    const int wave = tid >> 6, lane = tid & 63;
    if (lane == 0) { ss[wave] = s; ss2[wave] = s2; }
    __syncthreads();
    s = ss[0] + ss[1] + ss[2];
    s2 = ss2[0] + ss2[1] + ss2[2];
    const float mu = s * (1.0f / 768.0f);
    float var = s2 * (1.0f / 768.0f) - mu * mu;
    const float inv = rsqrtf(var + LN_EPS);

    unsigned short pk[4];
#pragma unroll
    for (int i = 0; i < 4; ++i) {
        const int d = d0 + i;
        const float v = (vals[i] - mu) * inv * g[d] + b[d];
        bf16 bb = __float2bfloat16(v);
        pk[i] = *(unsigned short*)&bb;
    }
    *(ushort4*)(out + (size_t)n * DMODEL + d0) = *(ushort4*)pk;
}

// ---------------------------------------------------------------------------
// Output projection v2: 128-row blocks, region-select. grid = (34, 12).
// Wave owns 32 rows as 2 groups sharing B-frags: 8 MFMA per 6 ds_read_b128.
// fp32 out.
// ---------------------------------------------------------------------------
__global__ __launch_bounds__(256, 2) void out_kernel(
    const bf16* __restrict__ Lb, const bf16* __restrict__ wo,
    const float* __restrict__ bo_p, const float* __restrict__ bo_d,
    float* __restrict__ out) {
    __shared__ bf16 As[128][32];
    __shared__ bf16 Bs[64][32];

    const int tid = threadIdx.x;
    const int wave = tid >> 6, lane = tid & 63;
    const int quad = lane >> 4, l16 = lane & 15;
    const int bx = blockIdx.x;
    const int is_det = bx >= 33;
    const int row0 = is_det ? NP : bx * 128;
    const int Mlim = is_det ? NT : NP;
    const int col0 = blockIdx.y * 64;
    const size_t nw = (size_t)DMODEL * DMODEL;
    const bf16* B = wo + (is_det ? nw : 0);
    const float* bias = is_det ? bo_d : bo_p;

    const f32x4 z4 = {0.f, 0.f, 0.f, 0.f};
    f32x4 acc[2][4];
#pragma unroll
    for (int gg = 0; gg < 2; ++gg)
#pragma unroll
        for (int t = 0; t < 4; ++t) acc[gg][t] = z4;

    // staging: As 128x32 (2 uint4/thread, same row), Bs 64x32 (1 uint4/thread)
    const int arow = tid >> 1;              // 0..127
    const int acol = (tid & 1) * 16;        // 0 or 16
    int a_r = row0 + arow;
    if (a_r >= Mlim) a_r = Mlim - 1;
    const bf16* ap = Lb + (size_t)a_r * DMODEL + acol;
    const int brow = tid >> 2;              // 0..63
    const int bcol = (tid & 3) * 8;
    const bf16* bp = B + (size_t)(col0 + brow) * DMODEL + bcol;

    uint4 areg0 = *(const uint4*)(ap);
    uint4 areg1 = *(const uint4*)(ap + 8);
    uint4 breg  = *(const uint4*)(bp);

    for (int k0 = 0; k0 < DMODEL; k0 += 32) {
        __syncthreads();
        *(uint4*)(&As[arow][acol]) = areg0;
        *(uint4*)(&As[arow][acol + 8]) = areg1;
        *(uint4*)(&Bs[brow][bcol]) = breg;
        if (k0 + 32 < DMODEL) {
            areg0 = *(const uint4*)(ap + k0 + 32);
            areg1 = *(const uint4*)(ap + k0 + 40);
            breg  = *(const uint4*)(bp + k0 + 32);
        }
        __asm__ volatile("s_waitcnt lgkmcnt(0)" ::: "memory");
        __builtin_amdgcn_s_barrier();
        __asm__ volatile("" ::: "memory");
        frag8 af[2], bfq[4];
#pragma unroll
        for (int gg = 0; gg < 2; ++gg)
            af[gg] = *(const frag8*)(&As[wave * 32 + gg * 16 + l16][quad * 8]);
#pragma unroll
        for (int t = 0; t < 4; ++t)
            bfq[t] = *(const frag8*)(&Bs[t * 16 + l16][quad * 8]);
#pragma unroll
        for (int gg = 0; gg < 2; ++gg)
#pragma unroll
            for (int t = 0; t < 4; ++t)
                acc[gg][t] = __builtin_amdgcn_mfma_f32_16x16x32_bf16(af[gg], bfq[t], acc[gg][t], 0, 0, 0);
        __asm__ volatile("" ::: "memory");
    }

#pragma unroll
    for (int gg = 0; gg < 2; ++gg) {
        const int rbase = row0 + wave * 32 + gg * 16 + quad * 4;
#pragma unroll
        for (int t = 0; t < 4; ++t) {
            const int c = col0 + t * 16 + l16;
            const float bv = bias[c];
#pragma unroll
            for (int j = 0; j < 4; ++j) {
                const int r = rbase + j;
                if (r < Mlim) out[(size_t)r * DMODEL + c] = acc[gg][t][j] + bv;
            }
        }
    }
}

// ---------------------------------------------------------------------------
extern "C" void kernel_launch(void* const* d_in, const int* in_sizes, int n_in,
                              void* d_out, int out_size, void* d_ws, size_t ws_size,
                              hipStream_t stream) {
    const float* x    = (const float*)d_in[0];
    const float* wq_p = (const float*)d_in[1];
    const float* wk_p = (const float*)d_in[2];
    const float* wv_p = (const float*)d_in[3];
    const float* wq_d = (const float*)d_in[4];
    const float* wk_d = (const float*)d_in[5];
    const float* wv_d = (const float*)d_in[6];
    const float* bq_p = (const float*)d_in[7];
    const float* bv_p = (const float*)d_in[8];
    const float* bq_d = (const float*)d_in[9];
    const float* bv_d = (const float*)d_in[10];
    const float* ln_g = (const float*)d_in[11];
    const float* ln_b = (const float*)d_in[12];
    const float* wo_p = (const float*)d_in[13];
    const float* bo_p = (const float*)d_in[14];
    const float* wo_d = (const float*)d_in[15];
    const float* bo_d = (const float*)d_in[16];
    float* out = (float*)d_out;

    const size_t nx  = (size_t)NT * DMODEL;       // 3,303,168
    const size_t nsw = (size_t)NHEAD * NCHUNK * CHUNKSZ;  // 3,342,336
    const size_t nw  = (size_t)DMODEL * DMODEL;   // 589,824

    // fixed region
    char* ws = (char*)d_ws;
    bf16* xb   = (bf16*)ws; ws += nx * 2;         // reused as Lb after qkv
    bf16* wqkv = (bf16*)ws; ws += 6 * nw * 2;
    bf16* wob  = (bf16*)ws; ws += 2 * nw * 2;
    bf16* Qb   = (bf16*)ws; ws += nx * 2;
    bf16* Ksw  = (bf16*)ws; ws += nsw * 2;
    bf16* Vsw  = (bf16*)ws; ws += nsw * 2;
    const size_t fixed = (size_t)(ws - (char*)d_ws);

    // per-split region: O_part (fp32 NT x 768) + l_part (fp32 12 x NTP)
    const size_t per_split = nx * 4 + (size_t)NHEAD * NTP * 4;
    int nsplit = 1;
    if (ws_size >= fixed + 4 * per_split) nsplit = 4;
    else if (ws_size >= fixed + 2 * per_split) nsplit = 2;
    const int cpb = NCHUNK / nsplit;              // 68 divisible by 1/2/4

    float* O_part = (float*)ws;
    float* l_part = (float*)(ws + (size_t)nsplit * nx * 4);
    bf16* Lb = xb;   // xb dead after qkv_kernel

    const int total = (int)(nx + 8 * nw);
    cast_all_kernel<<<dim3((total / 4 + 255) / 256), dim3(256), 0, stream>>>(
        x, wq_p, wk_p, wv_p, wq_d, wk_d, wv_d, wo_p, wo_d, xb, (int)nx, (int)nw, total);

    qkv_kernel<<<dim3(68, 12), dim3(256), 0, stream>>>(
        xb, wqkv, bq_p, bq_d, bv_p, bv_d, Qb, Ksw, Vsw);

    attn_kernel<<<dim3(34 * NHEAD * nsplit), dim3(256), 0, stream>>>(
        Qb, Ksw, Vsw, O_part, l_part, cpb);

    reduce_ln_kernel<<<dim3(NT), dim3(192), 0, stream>>>(
        O_part, l_part, ln_g, ln_b, Lb, nsplit);

    out_kernel<<<dim3(34, 12), dim3(256), 0, stream>>>(Lb, wob, bo_p, bo_d, out);
}

// Round 10
// 229.870 us; speedup vs baseline: 2.4248x; 1.0125x over previous
//
#include <hip/hip_runtime.h>
#include <hip/hip_bf16.h>

// Problem constants
#define NT 4301   // total tokens
#define NP 4201   // patch tokens (use *_p weights)
#define NDET 100  // detection tokens (use *_d weights)
#define DMODEL 768
#define NHEAD 12
#define HD 64
#define LN_EPS 1e-5f
#define LOG2E 1.4426950408889634f
#define QSCALE (0.125f * LOG2E)   // attn scale folded with log2(e): softmax in exp2 domain
#define NTP 4352                  // padded token count (34*128 = 68*64)
#define NCHUNK 68                 // ceil(4301/64)
#define FRAGSZ 512                // elems per frag blob: 64 lanes x 8 bf16
#define CHUNKSZ 4096              // elems per (head,chunk): 8 frags x 512

typedef __hip_bfloat16 bf16;
typedef __attribute__((ext_vector_type(4))) float f32x4;
typedef __attribute__((ext_vector_type(8))) short frag8;  // 8 bf16 in 4 VGPRs
typedef __attribute__((ext_vector_type(2))) unsigned int u32x2;

// permlane swap helpers (gfx950). Builtin returns {new_dst, new_src}; both used.
static __device__ __forceinline__ void permlane32_swap(unsigned& a, unsigned& b) {
#if __has_builtin(__builtin_amdgcn_permlane32_swap)
    u32x2 r = __builtin_amdgcn_permlane32_swap(a, b, false, false);
    a = r[0]; b = r[1];
#else
    asm("v_permlane32_swap_b32 %0, %1" : "+v"(a), "+v"(b));
#endif
}
static __device__ __forceinline__ void permlane16_swap(unsigned& a, unsigned& b) {
#if __has_builtin(__builtin_amdgcn_permlane16_swap)
    u32x2 r = __builtin_amdgcn_permlane16_swap(a, b, false, false);
    a = r[0]; b = r[1];
#else
    asm("v_permlane16_swap_b32 %0, %1" : "+v"(a), "+v"(b));
#endif
}

// native exp2 (no OCML guard code); v_exp_f32 handles the full f32 range.
static __device__ __forceinline__ float fast_exp2(float x) {
#if __has_builtin(__builtin_amdgcn_exp2f)
    return __builtin_amdgcn_exp2f(x);
#else
    return __builtin_exp2f(x);
#endif
}

// Pack two f32 -> bf16x2 (a -> low16, b -> high16) in ONE v_perm_b32.
// Truncation (no round-to-nearest): softmax divides sum(P*V) by sum(P), so
// the uniform downward bias ~cancels; saves 2 VALU adds per pair vs
// round-half-up.
static __device__ __forceinline__ unsigned pack_bf16_tr(float a, float b) {
    return __builtin_amdgcn_perm(__builtin_bit_cast(unsigned, b),
                                 __builtin_bit_cast(unsigned, a), 0x07060302u);
}

// async global->LDS, 16B per lane. LDS dest = wave-uniform base + lane*16
// (m104); global src is per-lane.
static __device__ __forceinline__ void gload16(const bf16* g, bf16* l) {
    __builtin_amdgcn_global_load_lds(
        (const __attribute__((address_space(1))) void*)g,
        (__attribute__((address_space(3))) void*)l, 16, 0, 0);
}

// ---------------------------------------------------------------------------
// One fused cast: x + 8 weight matrices fp32->bf16 into contiguous ws region
// ---------------------------------------------------------------------------
__global__ __launch_bounds__(256) void cast_all_kernel(
    const float* __restrict__ x,
    const float* __restrict__ w0, const float* __restrict__ w1,
    const float* __restrict__ w2, const float* __restrict__ w3,
    const float* __restrict__ w4, const float* __restrict__ w5,
    const float* __restrict__ w6, const float* __restrict__ w7,
    bf16* __restrict__ dst, int nx, int nw, int total) {
    int i4 = (blockIdx.x * 256 + threadIdx.x) * 4;
    if (i4 >= total) return;
    const float* s;
    int off;
    if (i4 < nx) {
        s = x; off = i4;
    } else {
        int r = i4 - nx;
        int w = r / nw;
        off = r - w * nw;
        s = w0;
        if (w == 1) s = w1; else if (w == 2) s = w2; else if (w == 3) s = w3;
        else if (w == 4) s = w4; else if (w == 5) s = w5;
        else if (w == 6) s = w6; else if (w == 7) s = w7;
    }
    float4 v = *(const float4*)(s + off);
    bf16 o[4] = {__float2bfloat16(v.x), __float2bfloat16(v.y),
                 __float2bfloat16(v.z), __float2bfloat16(v.w)};
    *(ushort4*)(dst + i4) = *(ushort4*)o;
}

// ---------------------------------------------------------------------------
// Fused QKV v3: v16-style staging. Double-buffered LDS filled by
// global_load_lds (no VGPR round-trip), ONE barrier per K-step. Layouts are
// linear in tid (As byte off = 16*tid; each Bs region = 16*tid), so gload's
// wave-uniform-base + lane*16 lands exactly on the old [srow][scol8] slots.
// grid = (68, 12). Outputs: Q*QSCALE row-major; K/V pre-swizzled frag order.
// ---------------------------------------------------------------------------
__global__ __launch_bounds__(256, 4) void qkv_kernel(
    const bf16* __restrict__ xb, const bf16* __restrict__ wbase,
    const float* __restrict__ bq_p, const float* __restrict__ bq_d,
    const float* __restrict__ bv_p, const float* __restrict__ bv_d,
    bf16* __restrict__ Qb, bf16* __restrict__ Ksw, bf16* __restrict__ Vsw) {
    __shared__ bf16 As[2][64][32];
    __shared__ bf16 Bs[2][192][32];   // rows 0-63: wq, 64-127: wk, 128-191: wv

    const int tid = threadIdx.x;
    const int wave = tid >> 6, lane = tid & 63;
    const int quad = lane >> 4, l16 = lane & 15;
    const int bx = blockIdx.x;
    const int h = blockIdx.y;
    const int is_det = bx >= 66;
    const int row0 = is_det ? NP + (bx - 66) * 64 : bx * 64;
    const int Mlim = is_det ? NT : NP;
    const int col0 = h * 64;
    const size_t nw = (size_t)DMODEL * DMODEL;
    const bf16* W = wbase + (is_det ? 3 * nw : 0);

    const f32x4 z4 = {0.f, 0.f, 0.f, 0.f};
    f32x4 acc[4][3];
#pragma unroll
    for (int r4 = 0; r4 < 4; ++r4)
#pragma unroll
        for (int f = 0; f < 3; ++f) acc[r4][f] = z4;

    const int srow = tid >> 2;          // 0..63
    const int scol8 = (tid & 3) * 8;    // 0,8,16,24
    int a_r = row0 + srow;
    if (a_r >= Mlim) a_r = Mlim - 1;
    const bf16* ap = xb + (size_t)a_r * DMODEL + scol8;
    const bf16* bp = W + (size_t)(col0 + srow) * DMODEL + scol8;

    // wave-uniform LDS bases (each wave stages its 1 KB quarter per region)
    bf16* asb[2] = {&As[0][0][0] + wave * 512, &As[1][0][0] + wave * 512};
    bf16* bsb[2] = {&Bs[0][0][0] + wave * 512, &Bs[1][0][0] + wave * 512};

    // prologue: stage k0=0 into buffer 0
    {
        gload16(ap, asb[0]);
        gload16(bp, bsb[0]);
        gload16(bp + nw, bsb[0] + 2048);
        gload16(bp + 2 * nw, bsb[0] + 4096);
    }
    __asm__ volatile("s_waitcnt vmcnt(0)" ::: "memory");
    __builtin_amdgcn_s_barrier();
    __asm__ volatile("" ::: "memory");

    int p = 0;
    for (int k0 = 0; k0 < DMODEL; k0 += 32) {
        if (k0 + 32 < DMODEL) {
            const int kn = k0 + 32;
            gload16(ap + kn, asb[p ^ 1]);
            gload16(bp + kn, bsb[p ^ 1]);
            gload16(bp + nw + kn, bsb[p ^ 1] + 2048);
            gload16(bp + 2 * nw + kn, bsb[p ^ 1] + 4096);
        }
        frag8 af[4], bfr[3];
#pragma unroll
        for (int r4 = 0; r4 < 4; ++r4)
            af[r4] = *(const frag8*)(&As[p][r4 * 16 + l16][quad * 8]);
#pragma unroll
        for (int f = 0; f < 3; ++f)
            bfr[f] = *(const frag8*)(&Bs[p][wave * 48 + f * 16 + l16][quad * 8]);
#pragma unroll
        for (int r4 = 0; r4 < 4; ++r4)
#pragma unroll
            for (int f = 0; f < 3; ++f)
                acc[r4][f] = __builtin_amdgcn_mfma_f32_16x16x32_bf16(af[r4], bfr[f], acc[r4][f], 0, 0, 0);
        // single barrier: next-step stage writes landed; all waves done reading p
        __asm__ volatile("s_waitcnt vmcnt(0)" ::: "memory");
        __builtin_amdgcn_s_barrier();
        __asm__ volatile("" ::: "memory");
        p ^= 1;
    }

    // epilogue: wave w covers logical cols [w*48, w*48+48); 16-col group oc=3w+f
#pragma unroll
    for (int f = 0; f < 3; ++f) {
        const int oc = 3 * wave + f;          // 0..11
        const int opi = oc >> 2;              // 0=Q 1=K 2=V
        const int cin = (oc & 3) * 16 + l16;  // head-dim 0..63
        const int c = col0 + cin;             // global dim
        float bv = 0.f, scale = 1.f;
        if (opi == 0) { bv = (is_det ? bq_d : bq_p)[c]; scale = QSCALE; }
        else if (opi == 2) { bv = (is_det ? bv_d : bv_p)[c]; }
#pragma unroll
        for (int r4 = 0; r4 < 4; ++r4) {
#pragma unroll
            for (int j = 0; j < 4; ++j) {
                const int r = row0 + r4 * 16 + quad * 4 + j;
                if (r >= Mlim) continue;
                const bf16 val = __float2bfloat16((acc[r4][f][j] + bv) * scale);
                if (opi == 0) {
                    Qb[(size_t)r * DMODEL + c] = val;
                } else if (opi == 1) {
                    const int cc = r >> 6, tf = (r >> 4) & 3, ln = r & 15;
                    const int s = cin >> 5, qd = (cin >> 3) & 3, je = cin & 7;
                    Ksw[((size_t)(h * NCHUNK + cc) * 8 + tf * 2 + s) * FRAGSZ +
                        (qd * 16 + ln) * 8 + je] = val;
                } else {
                    const int t = cin >> 4, le = cin & 15;
                    const int cc = r >> 6, rr = r & 63;
                    const int sv = rr >> 5, qv = (rr >> 3) & 3, je = rr & 7;
                    Vsw[((size_t)(h * NCHUNK + cc) * 8 + t * 2 + sv) * FRAGSZ +
                        (qv * 16 + le) * 8 + je] = val;
                }
            }
        }
    }
}

// ---------------------------------------------------------------------------
// Flash attention v16 (unchanged from R9 best): 4-wave/256-thr blocks, 128
// q-rows, 32 KB double-buffered K/V via gload_lds, one barrier per chunk,
// swapped QK^T + in-register P (permlane), truncating pack.
// ---------------------------------------------------------------------------
__global__ __launch_bounds__(256, 4) void attn_kernel(
    const bf16* __restrict__ Q, const bf16* __restrict__ Ksw,
    const bf16* __restrict__ Vsw, float* __restrict__ O_part,
    float* __restrict__ l_part, int cpb) {
    __shared__ bf16 KV[2][16][FRAGSZ];   // [buf][frag: 0-7 K, 8-15 V][lane*8]

    const int tid = threadIdx.x;
    const int wave = tid >> 6, lane = tid & 63;
    const int quad = lane >> 4, l16 = lane & 15;

    // decode (bx, h, z) from 1D id; XCD-chunked when blocks/XCD % 34 == 0
    int bx, h, z;
    {
        const int id = blockIdx.x;
        const int nblk = gridDim.x;
        const int per = nblk >> 3;
        if ((nblk & 7) == 0 && per % 34 == 0) {
            const int ppx = per / 34;                 // (h,z) pairs per XCD
            const int q = id >> 3;
            const int pair = (id & 7) * ppx + q / 34;
            bx = q % 34;
            h = pair % NHEAD; z = pair / NHEAD;
        } else {
            bx = id % 34; h = (id / 34) % NHEAD; z = id / (34 * NHEAD);
        }
    }
    const int qbase = bx * 128;
    const int hoff = h * HD;
    const int c0 = z * cpb, c1 = c0 + cpb;

    frag8 ones;
#pragma unroll
    for (int j = 0; j < 8; ++j) ones[j] = (short)0x3F80;

    // Q fragments for 2 row-groups: rows qbase + wave*32 + g*16 + l16.
    frag8 qf[2][2];
#pragma unroll
    for (int g = 0; g < 2; ++g) {
        int qr = qbase + wave * 32 + g * 16 + l16;
        if (qr >= NT) qr = NT - 1;
#pragma unroll
        for (int s = 0; s < 2; ++s)
            qf[g][s] = *(const frag8*)(Q + (size_t)qr * DMODEL + hoff + s * 32 + quad * 8);
    }

    // staging: wave 0/1 -> K frags 0-3/4-7, wave 2/3 -> V frags 0-3/4-7.
    const bf16* kb0 = Ksw + (size_t)h * NCHUNK * CHUNKSZ + lane * 8;
    const bf16* vb0 = Vsw + (size_t)h * NCHUNK * CHUNKSZ + lane * 8;
    const bf16* sb = (wave < 2) ? kb0 : vb0;
    const int foff = (wave & 1) * 4;      // frag index within K or V blob
    const int fbase = 4 * wave;           // LDS frag row

    const f32x4 z4 = {0.f, 0.f, 0.f, 0.f};
    f32x4 accO[2][4], accL[2];
#pragma unroll
    for (int g = 0; g < 2; ++g) {
        accL[g] = z4;
#pragma unroll
        for (int t = 0; t < 4; ++t) accO[g][t] = z4;
    }

    // prologue: stage chunk c0 into buffer 0, drain, sync
    {
        const bf16* s = sb + (size_t)c0 * CHUNKSZ + foff * FRAGSZ;
#pragma unroll
        for (int i = 0; i < 4; ++i)
            gload16(s + i * FRAGSZ, &KV[0][fbase + i][0]);
    }
    __asm__ volatile("s_waitcnt vmcnt(0)" ::: "memory");
    __builtin_amdgcn_s_barrier();
    __asm__ volatile("" ::: "memory");

    int p = 0;
    for (int c = c0; c < c1; ++c) {
        // stage next chunk into the other buffer; flight hidden under compute
        if (c + 1 < c1) {
            const bf16* s = sb + (size_t)(c + 1) * CHUNKSZ + foff * FRAGSZ;
#pragma unroll
            for (int i = 0; i < 4; ++i)
                gload16(s + i * FRAGSZ, &KV[p ^ 1][fbase + i][0]);
        }

        // S^T = K @ Q^T; kf read per-t at point of use (8 live K VGPRs)
        f32x4 S[2][4];
#pragma unroll
        for (int t = 0; t < 4; ++t) {
            const frag8 k0 = *(const frag8*)(&KV[p][t * 2 + 0][lane * 8]);
            const frag8 k1 = *(const frag8*)(&KV[p][t * 2 + 1][lane * 8]);
#pragma unroll
            for (int g = 0; g < 2; ++g) {
                f32x4 s0 = __builtin_amdgcn_mfma_f32_16x16x32_bf16(k0, qf[g][0], z4, 0, 0, 0);
                S[g][t]  = __builtin_amdgcn_mfma_f32_16x16x32_bf16(k1, qf[g][1], s0, 0, 0, 0);
            }
        }
        if (c == NCHUNK - 1) {
            const int kb = c * 64 + quad * 4;   // k row index base for this lane
#pragma unroll
            for (int t = 0; t < 4; ++t)
#pragma unroll
                for (int j = 0; j < 4; ++j)
                    if (kb + t * 16 + j >= NT) {
                        S[0][t][j] = -1e30f;
                        S[1][t][j] = -1e30f;
                    }
        }

        // softmax: exp2 -> 1-op truncating pack -> permlane assembly
        frag8 pf[2][2];   // [g][s]
#pragma unroll
        for (int g = 0; g < 2; ++g) {
            unsigned lo[4], hi[4];
#pragma unroll
            for (int t = 0; t < 4; ++t) {
                lo[t] = pack_bf16_tr(fast_exp2(S[g][t][0]), fast_exp2(S[g][t][1]));
                hi[t] = pack_bf16_tr(fast_exp2(S[g][t][2]), fast_exp2(S[g][t][3]));
            }
#pragma unroll
            for (int s = 0; s < 2; ++s) {
                unsigned A = lo[2 * s], B = hi[2 * s];
                unsigned C = lo[2 * s + 1], D = hi[2 * s + 1];
                permlane32_swap(A, C);
                permlane32_swap(B, D);
                permlane16_swap(A, C);
                permlane16_swap(B, D);
                union { unsigned u[4]; frag8 f; } pu;
                pu.u[0] = A; pu.u[1] = B; pu.u[2] = C; pu.u[3] = D;
                pf[g][s] = pu.f;
                accL[g] = __builtin_amdgcn_mfma_f32_16x16x32_bf16(pf[g][s], ones, accL[g], 0, 0, 0);
            }
        }

        // O += P @ V ; vf read per (s,t), shared across both row-groups
#pragma unroll
        for (int s = 0; s < 2; ++s)
#pragma unroll
            for (int t = 0; t < 4; ++t) {
                const frag8 v = *(const frag8*)(&KV[p][8 + t * 2 + s][lane * 8]);
#pragma unroll
                for (int g = 0; g < 2; ++g)
                    accO[g][t] = __builtin_amdgcn_mfma_f32_16x16x32_bf16(pf[g][s], v, accO[g][t], 0, 0, 0);
            }

        // single barrier per chunk: stage writes landed (vmcnt 0, hidden
        // under the compute above) and every wave is done reading buf p.
        __asm__ volatile("s_waitcnt vmcnt(0)" ::: "memory");
        __builtin_amdgcn_s_barrier();
        __asm__ volatile("" ::: "memory");
        p ^= 1;
    }

    // write fp32 partials
    float* Op = O_part + (size_t)z * NT * DMODEL;
#pragma unroll
    for (int g = 0; g < 2; ++g)
#pragma unroll
        for (int j = 0; j < 4; ++j) {
            const int r = qbase + wave * 32 + g * 16 + quad * 4 + j;
            if (r < NT) {
#pragma unroll
                for (int t = 0; t < 4; ++t)
                    Op[(size_t)r * DMODEL + hoff + t * 16 + l16] = accO[g][t][j];
                if (l16 == 0)
                    l_part[((size_t)z * NHEAD + h) * NTP + r] = accL[g][j];
            }
        }
}

// ---------------------------------------------------------------------------
// Reduce kv-splits + per-head normalize + LayerNorm. grid = (NT), 192 thr.
// Each thread owns 4 consecutive dims (float4 loads; same head per quad).
// ---------------------------------------------------------------------------
__global__ __launch_bounds__(192) void reduce_ln_kernel(
    const float* __restrict__ O_part, const float* __restrict__ l_part,
    const float* __restrict__ g, const float* __restrict__ b,
    bf16* __restrict__ out, int nsplit) {
    const int n = blockIdx.x;
    const int tid = threadIdx.x;
    const int d0 = tid * 4;
    const int hh = d0 >> 6;

    float4 o = make_float4(0.f, 0.f, 0.f, 0.f);
    float lv = 0.f;
    for (int s = 0; s < nsplit; ++s) {
        float4 v = *(const float4*)(O_part + ((size_t)s * NT + n) * DMODEL + d0);
        o.x += v.x; o.y += v.y; o.z += v.z; o.w += v.w;
        lv += l_part[((size_t)s * NHEAD + hh) * NTP + n];
    }
    const float inv_l = 1.0f / lv;
    float vals[4] = {o.x * inv_l, o.y * inv_l, o.z * inv_l, o.w * inv_l};

    float s = vals[0] + vals[1] + vals[2] + vals[3];
    float s2 = vals[0] * vals[0] + vals[1] * vals[1] + vals[2] * vals[2] + vals[3] * vals[3];
#pragma unroll
    for (int off = 1; off < 64; off <<= 1) {
        s += __shfl_xor(s, off);
        s2 += __shfl_xor(s2, off);
    }
    __shared__ float ss[3], ss2[3];
    const int wave = tid >> 6, lane = tid & 63;
    if (lane == 0) { ss[wave] = s; ss2[wave] = s2; }
    __syncthreads();
    s = ss[0] + ss[1] + ss[2];
    s2 = ss2[0] + ss2[1] + ss2[2];
    const float mu = s * (1.0f / 768.0f);
    float var = s2 * (1.0f / 768.0f) - mu * mu;
    const float inv = rsqrtf(var + LN_EPS);

    unsigned short pk[4];
#pragma unroll
    for (int i = 0; i < 4; ++i) {
        const int d = d0 + i;
        const float v = (vals[i] - mu) * inv * g[d] + b[d];
        bf16 bb = __float2bfloat16(v);
        pk[i] = *(unsigned short*)&bb;
    }
    *(ushort4*)(out + (size_t)n * DMODEL + d0) = *(ushort4*)pk;
}

// ---------------------------------------------------------------------------
// Output projection v3: 128-row blocks, region-select. grid = (34, 12).
// (256,4): cap 128 regs/wave (~90 live) -> up to 4 blocks/SIMD-pool vs v2's
// 2-wave grant (R6's proven occupancy lever). fp32 out.
// ---------------------------------------------------------------------------
__global__ __launch_bounds__(256, 4) void out_kernel(
    const bf16* __restrict__ Lb, const bf16* __restrict__ wo,
    const float* __restrict__ bo_p, const float* __restrict__ bo_d,
    float* __restrict__ out) {
    __shared__ bf16 As[128][32];
    __shared__ bf16 Bs[64][32];

    const int tid = threadIdx.x;
    const int wave = tid >> 6, lane = tid & 63;
    const int quad = lane >> 4, l16 = lane & 15;
    const int bx = blockIdx.x;
    const int is_det = bx >= 33;
    const int row0 = is_det ? NP : bx * 128;
    const int Mlim = is_det ? NT : NP;
    const int col0 = blockIdx.y * 64;
    const size_t nw = (size_t)DMODEL * DMODEL;
    const bf16* B = wo + (is_det ? nw : 0);
    const float* bias = is_det ? bo_d : bo_p;

    const f32x4 z4 = {0.f, 0.f, 0.f, 0.f};
    f32x4 acc[2][4];
#pragma unroll
    for (int gg = 0; gg < 2; ++gg)
#pragma unroll
        for (int t = 0; t < 4; ++t) acc[gg][t] = z4;

    // staging: As 128x32 (2 uint4/thread, same row), Bs 64x32 (1 uint4/thread)
    const int arow = tid >> 1;              // 0..127
    const int acol = (tid & 1) * 16;        // 0 or 16
    int a_r = row0 + arow;
    if (a_r >= Mlim) a_r = Mlim - 1;
    const bf16* ap = Lb + (size_t)a_r * DMODEL + acol;
    const int brow = tid >> 2;              // 0..63
    const int bcol = (tid & 3) * 8;
    const bf16* bp = B + (size_t)(col0 + brow) * DMODEL + bcol;

    uint4 areg0 = *(const uint4*)(ap);
    uint4 areg1 = *(const uint4*)(ap + 8);
    uint4 breg  = *(const uint4*)(bp);

    for (int k0 = 0; k0 < DMODEL; k0 += 32) {
        __syncthreads();
        *(uint4*)(&As[arow][acol]) = areg0;
        *(uint4*)(&As[arow][acol + 8]) = areg1;
        *(uint4*)(&Bs[brow][bcol]) = breg;
        if (k0 + 32 < DMODEL) {
            areg0 = *(const uint4*)(ap + k0 + 32);
            areg1 = *(const uint4*)(ap + k0 + 40);
            breg  = *(const uint4*)(bp + k0 + 32);
        }
        __asm__ volatile("s_waitcnt lgkmcnt(0)" ::: "memory");
        __builtin_amdgcn_s_barrier();
        __asm__ volatile("" ::: "memory");
        frag8 af[2], bfq[4];
#pragma unroll
        for (int gg = 0; gg < 2; ++gg)
            af[gg] = *(const frag8*)(&As[wave * 32 + gg * 16 + l16][quad * 8]);
#pragma unroll
        for (int t = 0; t < 4; ++t)
            bfq[t] = *(const frag8*)(&Bs[t * 16 + l16][quad * 8]);
#pragma unroll
        for (int gg = 0; gg < 2; ++gg)
#pragma unroll
            for (int t = 0; t < 4; ++t)
                acc[gg][t] = __builtin_amdgcn_mfma_f32_16x16x32_bf16(af[gg], bfq[t], acc[gg][t], 0, 0, 0);
        __asm__ volatile("" ::: "memory");
    }

#pragma unroll
    for (int gg = 0; gg < 2; ++gg) {
        const int rbase = row0 + wave * 32 + gg * 16 + quad * 4;
#pragma unroll
        for (int t = 0; t < 4; ++t) {
            const int c = col0 + t * 16 + l16;
            const float bv = bias[c];
#pragma unroll
            for (int j = 0; j < 4; ++j) {
                const int r = rbase + j;
                if (r < Mlim) out[(size_t)r * DMODEL + c] = acc[gg][t][j] + bv;
            }
        }
    }
}

// ---------------------------------------------------------------------------
extern "C" void kernel_launch(void* const* d_in, const int* in_sizes, int n_in,
                              void* d_out, int out_size, void* d_ws, size_t ws_size,
                              hipStream_t stream) {
    const float* x    = (const float*)d_in[0];
    const float* wq_p = (const float*)d_in[1];
    const float* wk_p = (const float*)d_in[2];
    const float* wv_p = (const float*)d_in[3];
    const float* wq_d = (const float*)d_in[4];
    const float* wk_d = (const float*)d_in[5];
    const float* wv_d = (const float*)d_in[6];
    const float* bq_p = (const float*)d_in[7];
    const float* bv_p = (const float*)d_in[8];
    const float* bq_d = (const float*)d_in[9];
    const float* bv_d = (const float*)d_in[10];
    const float* ln_g = (const float*)d_in[11];
    const float* ln_b = (const float*)d_in[12];
    const float* wo_p = (const float*)d_in[13];
    const float* bo_p = (const float*)d_in[14];
    const float* wo_d = (const float*)d_in[15];
    const float* bo_d = (const float*)d_in[16];
    float* out = (float*)d_out;

    const size_t nx  = (size_t)NT * DMODEL;       // 3,303,168
    const size_t nsw = (size_t)NHEAD * NCHUNK * CHUNKSZ;  // 3,342,336
    const size_t nw  = (size_t)DMODEL * DMODEL;   // 589,824

    // fixed region
    char* ws = (char*)d_ws;
    bf16* xb   = (bf16*)ws; ws += nx * 2;         // reused as Lb after qkv
    bf16* wqkv = (bf16*)ws; ws += 6 * nw * 2;
    bf16* wob  = (bf16*)ws; ws += 2 * nw * 2;
    bf16* Qb   = (bf16*)ws; ws += nx * 2;
    bf16* Ksw  = (bf16*)ws; ws += nsw * 2;
    bf16* Vsw  = (bf16*)ws; ws += nsw * 2;
    const size_t fixed = (size_t)(ws - (char*)d_ws);

    // per-split region: O_part (fp32 NT x 768) + l_part (fp32 12 x NTP)
    const size_t per_split = nx * 4 + (size_t)NHEAD * NTP * 4;
    int nsplit = 1;
    if (ws_size >= fixed + 4 * per_split) nsplit = 4;
    else if (ws_size >= fixed + 2 * per_split) nsplit = 2;
    const int cpb = NCHUNK / nsplit;              // 68 divisible by 1/2/4

    float* O_part = (float*)ws;
    float* l_part = (float*)(ws + (size_t)nsplit * nx * 4);
    bf16* Lb = xb;   // xb dead after qkv_kernel

    const int total = (int)(nx + 8 * nw);
    cast_all_kernel<<<dim3((total / 4 + 255) / 256), dim3(256), 0, stream>>>(
        x, wq_p, wk_p, wv_p, wq_d, wk_d, wv_d, wo_p, wo_d, xb, (int)nx, (int)nw, total);

    qkv_kernel<<<dim3(68, 12), dim3(256), 0, stream>>>(
        xb, wqkv, bq_p, bq_d, bv_p, bv_d, Qb, Ksw, Vsw);

    attn_kernel<<<dim3(34 * NHEAD * nsplit), dim3(256), 0, stream>>>(
        Qb, Ksw, Vsw, O_part, l_part, cpb);

    reduce_ln_kernel<<<dim3(NT), dim3(192), 0, stream>>>(
        O_part, l_part, ln_g, ln_b, Lb, nsplit);

    out_kernel<<<dim3(34, 12), dim3(256), 0, stream>>>(Lb, wob, bo_p, bo_d, out);
}